// Round 11
// baseline (370.194 us; speedup 1.0000x reference)
//
#include <hip/hip_runtime.h>
#include <cmath>
#include <cstdint>

typedef float floatx4 __attribute__((ext_vector_type(4)));
typedef float floatx16 __attribute__((ext_vector_type(16)));
typedef int   intx4   __attribute__((ext_vector_type(4)));
typedef int   intx8   __attribute__((ext_vector_type(8)));

#define EPS_ 1e-5f
#define QSCALE 0.17677669529663689f

// ---------- async global->LDS (16B per lane) ----------
__device__ __forceinline__ void gload16(const uint8_t* g, uint8_t* l) {
  __builtin_amdgcn_global_load_lds(
      (const __attribute__((address_space(1))) void*)g,
      (__attribute__((address_space(3))) void*)l, 16, 0, 0);
}

// ---------- fp8 e4m3 pack (word-select must be an immediate) ----------
template<bool HI>
__device__ __forceinline__ int pk_fp8(float a, float b, int old) {
  return __builtin_amdgcn_cvt_pk_fp8_f32(a, b, old, HI);
}
__device__ __forceinline__ int pk_fp8x4(float v0, float v1, float v2, float v3) {
  int w = pk_fp8<false>(v0, v1, 0);
  return pk_fp8<true>(v2, v3, w);
}

// ---------- bf16 helpers (RNE) ----------
__device__ __forceinline__ uint16_t f2bf(float f) {
  uint32_t u = __float_as_uint(f);
  return (uint16_t)((u + 0x7fffu + ((u >> 16) & 1u)) >> 16);
}
__device__ __forceinline__ float bf2f(uint16_t h) {
  return __uint_as_float(((uint32_t)h) << 16);
}

// ---------- fast GELU: x*sigmoid(1.702x) (error << fp8 quant; branch scaled by 1e-6) ----------
__device__ __forceinline__ float fast_gelu(float v) {
  const float t = __expf(-1.702f * v);
  return v * __builtin_amdgcn_rcpf(1.f + t);
}

// ---------- MX-scaled fp8 MFMA (unity scales: E8M0 127 = 2^0) ----------
__device__ __forceinline__ intx8 cat8(intx4 a, intx4 b) {
  return __builtin_shufflevector(a, b, 0, 1, 2, 3, 4, 5, 6, 7);
}
__device__ __forceinline__ floatx16 mfma_mx(intx8 a, intx8 b, floatx16 c) {
  return __builtin_amdgcn_mfma_scale_f32_32x32x64_f8f6f4(
      a, b, c, 0, 0, 0, 0x7F7F7F7F, 0, 0x7F7F7F7F);
}

// 16x16 fragment-major layout (proj/fc2 operands):
//   addr(m, k) = (m & ~15)*K + (k>>3)*128 + (m & 15)*8 + (k & 7)
// MX 32x32 A layout (qkv/fc1 A tokens): addr(m,k) = (m>>5)*32*K + (k>>5)*1024 + (m&31)*32 + (k&31)
// MX 32x32 B layout (Wq/W1, col-pair permuted): lane holds cols n0+2*(lane&31)+{0,1}

// ---------- fp32 weights -> fp8 frag-major 16x16 (col-permuted) ----------
template<int K>
__global__ void cvt_frag(const float* __restrict__ s, uint8_t* __restrict__ d, int n4) {
  const int i = blockIdx.x * 256 + threadIdx.x;
  if (i >= n4) return;
  const int kq = K >> 2;
  const int n = i / kq;
  const int k = (i - n * kq) << 2;
  const float4 v = ((const float4*)s)[i];
  const int panel = ((n >> 6) << 2) + (n & 3);
  const int lm = (n >> 2) & 15;
  const long addr = (long)panel * (16 * K) + ((k >> 3) << 7) + (lm << 3) + (k & 4);
  *(int*)(d + addr) = pk_fp8x4(v.x, v.y, v.z, v.w);
}

// ---------- fp32 weights -> fp8 MX 32x32 B layout (K=512; any N multiple of 64) ----------
__global__ void cvt_frag_mx512(const float* __restrict__ s, uint8_t* __restrict__ d, int n4) {
  const int i = blockIdx.x * 256 + threadIdx.x;
  if (i >= n4) return;
  const int n = i >> 7;               // out-channel (col), K/4 = 128
  const int k = (i & 127) << 2;
  const float4 v = ((const float4*)s)[i];
  const long addr = (long)(n >> 6) * 32768 + (n & 1) * 16384 + ((k >> 6) << 11)
                  + (((k >> 4) & 1) << 10)
                  + ((((k >> 5) & 1) << 5) + ((n & 63) >> 1)) * 16 + (k & 15);
  *(int*)(d + addr) = pk_fp8x4(v.x, v.y, v.z, v.w);
}

// ---------- LN1 stats over C for NCHW input ----------
__global__ __launch_bounds__(256)
void ln_stats_nchw(const float* __restrict__ x, float* __restrict__ mu, float* __restrict__ rs) {
  const int tl = threadIdx.x & 63;
  const int wv = threadIdx.x >> 6;
  const int t = blockIdx.x * 64 + tl;       // token = b*196 + p
  const int b = t / 196;
  const int p = t - b * 196;
  const float* xp = x + (long)b * 100352 + p;
  float s = 0.f, ss = 0.f;
  const int cbeg = wv * 128;
  for (int c = cbeg; c < cbeg + 128; ++c) {
    const float v = xp[(long)c * 196];
    s += v; ss += v * v;
  }
  __shared__ float sb[4][64], qb[4][64];
  sb[wv][tl] = s; qb[wv][tl] = ss;
  __syncthreads();
  if (wv == 0) {
    s  = sb[0][tl] + sb[1][tl] + sb[2][tl] + sb[3][tl];
    ss = qb[0][tl] + qb[1][tl] + qb[2][tl] + qb[3][tl];
    const float m = s * (1.f / 512.f);
    const float var = ss * (1.f / 512.f) - m * m;
    mu[t] = m;
    rs[t] = rsqrtf(var + EPS_);
  }
}

// ---------- LN1 apply: NCHW -> MX 32x32 A-layout fp8 tokens (feeds MX qkv) ----------
__global__ __launch_bounds__(256)
void ln1_apply(const float* __restrict__ x, const float* __restrict__ mu, const float* __restrict__ rs,
               const float* __restrict__ w, const float* __restrict__ bb, uint8_t* __restrict__ A) {
  __shared__ float tile[64][53];
  const int bid = blockIdx.x;
  const int ct = bid & 7;
  const int pt = (bid >> 3) & 3;
  const int b = bid >> 5;
  const int p0 = pt * 49, c0 = ct * 64;
  const long xbase = (long)b * 100352;
  for (int idx = threadIdx.x; idx < 3136; idx += 256) {
    const int cl = idx / 49;
    const int pl = idx - cl * 49;
    tile[cl][pl] = x[xbase + (long)(c0 + cl) * 196 + p0 + pl];
  }
  __syncthreads();
  const int tbase = b * 196 + p0;
  for (int idx = threadIdx.x; idx < 784; idx += 256) {
    const int pl = idx >> 4;                // 0..48
    const int cq = (idx & 15) << 2;         // 0..60 step 4
    const int t = tbase + pl;
    const int c = c0 + cq;
    const float m = mu[t], rr = rs[t];
    const float v0 = (tile[cq + 0][pl] - m) * rr * w[c + 0] + bb[c + 0];
    const float v1 = (tile[cq + 1][pl] - m) * rr * w[c + 1] + bb[c + 1];
    const float v2 = (tile[cq + 2][pl] - m) * rr * w[c + 2] + bb[c + 2];
    const float v3 = (tile[cq + 3][pl] - m) * rr * w[c + 3] + bb[c + 3];
    // MX A layout: (t>>5)*16384 + (c>>5)*1024 + (t&31)*32 + (c&31)
    const long addr = (long)(t >> 5) * 16384 + ((c >> 5) << 10) + ((t & 31) << 5) + (c & 31);
    *(int*)(A + addr) = pk_fp8x4(v0, v1, v2, v3);
  }
}

// ---------- LN2: one block per 16-token panel; X1 bf16 -> MX 32x32 A-layout fp8 ----------
__global__ __launch_bounds__(256)
void ln2_panel(const uint16_t* __restrict__ Xb, const float* __restrict__ S1,
               const float* __restrict__ S2, const float* __restrict__ w,
               const float* __restrict__ bb, uint8_t* __restrict__ Z) {
  __shared__ float xs[16 * 516];
  const int p = blockIdx.x;
  const int t0 = p * 16;
  for (int idx = threadIdx.x; idx < 1024; idx += 256) {
    const int tl = idx >> 6;                 // token 0..15
    const int c8 = (idx & 63) << 3;          // 0..504 step 8
    const uint4 raw = *(const uint4*)(Xb + ((long)(t0 + tl) << 9) + c8);
    float* xr = xs + tl * 516 + c8;
    xr[0] = bf2f((uint16_t)(raw.x & 0xffff)); xr[1] = bf2f((uint16_t)(raw.x >> 16));
    xr[2] = bf2f((uint16_t)(raw.y & 0xffff)); xr[3] = bf2f((uint16_t)(raw.y >> 16));
    xr[4] = bf2f((uint16_t)(raw.z & 0xffff)); xr[5] = bf2f((uint16_t)(raw.z >> 16));
    xr[6] = bf2f((uint16_t)(raw.w & 0xffff)); xr[7] = bf2f((uint16_t)(raw.w >> 16));
  }
  __syncthreads();
  for (int e = threadIdx.x; e < 2048; e += 256) {
    const int tl = e >> 7;             // token 0..15
    const int c  = (e & 127) << 2;     // channel 0..508 step 4
    const int t = t0 + tl;
    const float m = S1[t] * (1.f / 512.f);
    const float var = S2[t] * (1.f / 512.f) - m * m;
    const float r = rsqrtf(var + EPS_);
    const float* xr = xs + tl * 516 + c;
    const float v0 = (xr[0] - m) * r * w[c + 0] + bb[c + 0];
    const float v1 = (xr[1] - m) * r * w[c + 1] + bb[c + 1];
    const float v2 = (xr[2] - m) * r * w[c + 2] + bb[c + 2];
    const float v3 = (xr[3] - m) * r * w[c + 3] + bb[c + 3];
    // MX A layout: (t>>5)*16384 + (c>>5)*1024 + (t&31)*32 + (c&31)
    const long addr = (long)(t >> 5) * 16384 + ((c >> 5) << 10) + ((t & 31) << 5) + (c & 31);
    *(int*)(Z + addr) = pk_fp8x4(v0, v1, v2, v3);
  }
}

// ---------- fp8 16x16 MFMA GEMM (R1-verified structure): B LDS, A direct-global ----------
// 4 waves x (MI*16 rows) x 64 cols; A prefetch depth PD K-slices; XCD-swizzled grid.
// R11: PD=8 for fc2 (EPI3, K=2048) — issue-to-use 320 cyc covers ~200 cyc L2-hit latency
// on the Hb A-stream (PD=2 covered only 80). PD=2 elsewhere (codegen-identical to R10).
// All aP indices fold at compile time (ph/ksl fully unrolled) — no scratch.
// EPI 1: proj -> bf16 X1 = x + g1*(acc+b); fused LN2 raw-sum atomics
// EPI 3: fc2 -> f32 NCHW via LDS exchange (MI=2: 128 rows)
template<int MI, int K, int EPI, int NG, int T, int PD>
__global__ __launch_bounds__(256, 4)
void gemm_bl(const uint8_t* __restrict__ A, const uint8_t* __restrict__ Bw,
             const float* __restrict__ bias, const float* __restrict__ res,
             const uint16_t* __restrict__ resb, const float* __restrict__ gamma,
             uint8_t* __restrict__ outb, float* __restrict__ outf,
             uint16_t* __restrict__ outh, float* __restrict__ S1, float* __restrict__ S2,
             const int N) {
  const int kx = blockIdx.x & 7;
  const int sx = blockIdx.x >> 3;
  const int t = (sx / NG) * 8 + kx;
  if (t >= T) return;
  const int g = sx - (sx / NG) * NG;        // 64-col group
  __shared__ __align__(16) uint8_t Bs[(EPI == 3) ? 33280 : 32768];
  const int tid = threadIdx.x;
  const int wave = tid >> 6, lane = tid & 63;
  const int lm = lane & 15, lq = lane >> 4;
  const long m0 = (long)t * (MI * 64);
  const long n0 = (long)g << 6;
  const uint8_t* abase = A + (m0 + wave * MI * 16) * (long)K + (lane << 3);
  floatx4 acc[MI][4] = {};
  constexpr int NKS = K / 32;
  long aP[PD][MI];
  #pragma unroll
  for (int d = 0; d < PD; ++d)
    #pragma unroll
    for (int i = 0; i < MI; ++i)
      aP[d][i] = *(const long*)(abase + (long)i * 16 * K + (long)d * 512);
  #pragma unroll
  for (int ph = 0; ph < K / 512; ++ph) {
    const uint8_t* bsrc = Bw + n0 * K + ph * 8192;
    #pragma unroll
    for (int j = 0; j < 4; ++j)
      #pragma unroll
      for (int c = 0; c < 2; ++c)
        gload16(bsrc + (long)j * 16 * K + c * 4096 + tid * 16,
                Bs + j * 8192 + c * 4096 + tid * 16);
    __syncthreads();
    #pragma unroll
    for (int ksl = 0; ksl < 16; ++ksl) {
      const int sg = ph * 16 + ksl;
      long aC[MI];
      #pragma unroll
      for (int i = 0; i < MI; ++i) aC[i] = aP[sg % PD][i];
      if (sg + PD < NKS) {
        #pragma unroll
        for (int i = 0; i < MI; ++i)
          aP[sg % PD][i] = *(const long*)(abase + (long)i * 16 * K + (long)(sg + PD) * 512);
      }
      long bf[4];
      #pragma unroll
      for (int j = 0; j < 4; ++j)
        bf[j] = *(const long*)(Bs + j * 8192 + ksl * 512 + (lane << 3));
      __builtin_amdgcn_s_setprio(1);
      #pragma unroll
      for (int i = 0; i < MI; ++i)
        #pragma unroll
        for (int j = 0; j < 4; ++j)
          acc[i][j] = __builtin_amdgcn_mfma_f32_16x16x32_fp8_fp8(aC[i], bf[j], acc[i][j], 0, 0, 0);
      __builtin_amdgcn_s_setprio(0);
    }
    if (K / 512 > 1 && ph + 1 < K / 512) __syncthreads();
  }
  const int cb = (g << 6) + (lm << 2);
  const float4 b4 = *(const float4*)(bias + cb);
  float4 g4 = make_float4(0.f, 0.f, 0.f, 0.f);
  if (EPI == 1 || EPI == 3) g4 = *(const float4*)(gamma + cb);
  if (EPI != 3) {
    #pragma unroll
    for (int i = 0; i < MI; ++i) {
      #pragma unroll
      for (int r = 0; r < 4; ++r) {
        const long rowg = m0 + wave * MI * 16 + i * 16 + lq * 4 + r;
        float v0 = acc[i][0][r] + b4.x;
        float v1 = acc[i][1][r] + b4.y;
        float v2 = acc[i][2][r] + b4.z;
        float v3 = acc[i][3][r] + b4.w;
        {   // EPI 1
          const unsigned rg = (unsigned)rowg;
          const unsigned bi = rg / 196u;
          const unsigned p = rg - bi * 196u;
          const float* xr = res + (long)bi * 100352 + p;
          const float o0 = xr[(long)(cb + 0) * 196] + g4.x * v0;
          const float o1 = xr[(long)(cb + 1) * 196] + g4.y * v1;
          const float o2 = xr[(long)(cb + 2) * 196] + g4.z * v2;
          const float o3 = xr[(long)(cb + 3) * 196] + g4.w * v3;
          ushort4 hv;
          hv.x = f2bf(o0); hv.y = f2bf(o1); hv.z = f2bf(o2); hv.w = f2bf(o3);
          *(ushort4*)(outh + rowg * 512 + cb) = hv;
          const float q0 = bf2f(hv.x), q1 = bf2f(hv.y), q2 = bf2f(hv.z), q3 = bf2f(hv.w);
          float s = q0 + q1 + q2 + q3;
          float ss = q0 * q0 + q1 * q1 + q2 * q2 + q3 * q3;
          s += __shfl_xor(s, 1);  ss += __shfl_xor(ss, 1);
          s += __shfl_xor(s, 2);  ss += __shfl_xor(ss, 2);
          s += __shfl_xor(s, 4);  ss += __shfl_xor(ss, 4);
          s += __shfl_xor(s, 8);  ss += __shfl_xor(ss, 8);
          if (lm == 0) {
            atomicAdd(S1 + rowg, s);
            atomicAdd(S2 + rowg, ss);
          }
        }
      }
    }
  } else {
    // EPI 3 (MI=2): 128-row tile -> NCHW via LDS exchange, coalesced (stride 129)
    float* Tx = (float*)Bs;
    __syncthreads();
    #pragma unroll
    for (int i = 0; i < MI; ++i) {
      #pragma unroll
      for (int r = 0; r < 4; ++r) {
        const long rowg = m0 + wave * MI * 16 + i * 16 + lq * 4 + r;
        const int rl = (int)(rowg - m0);   // 0..127
        const ushort4 rb = *(const ushort4*)(resb + rowg * 512 + cb);
        Tx[(lm * 4 + 0) * 129 + rl] = bf2f(rb.x) + g4.x * (acc[i][0][r] + b4.x);
        Tx[(lm * 4 + 1) * 129 + rl] = bf2f(rb.y) + g4.y * (acc[i][1][r] + b4.y);
        Tx[(lm * 4 + 2) * 129 + rl] = bf2f(rb.z) + g4.z * (acc[i][2][r] + b4.z);
        Tx[(lm * 4 + 3) * 129 + rl] = bf2f(rb.w) + g4.w * (acc[i][3][r] + b4.w);
      }
    }
    __syncthreads();
    #pragma unroll
    for (int t2 = 0; t2 < 32; ++t2) {
      const int idx = t2 * 256 + tid;
      const int rl = idx & 127;
      const int ch = idx >> 7;
      const unsigned m = (unsigned)(m0 + rl);
      const unsigned bi = m / 196u;
      const unsigned p = m - bi * 196u;
      outf[(long)bi * 100352 + (long)(n0 + ch) * 196 + p] = Tx[ch * 129 + rl];
    }
  }
}

// ---------- qkv: MX-scaled fp8 GEMM, 32x32x64, K=512 -> fp8 token-major QKV ----------
// R10-verified: token-contiguous 16 KB LDS image -> coalesced token-major stores.
__global__ __launch_bounds__(256, 4)
void gemm_mx_qkv(const uint8_t* __restrict__ A, const uint8_t* __restrict__ Bw,
                 const float* __restrict__ bias, uint8_t* __restrict__ outb) {
  const int kx = blockIdx.x & 7;
  const int sx = blockIdx.x >> 3;
  const int t = (sx / 24) * 8 + kx;     // NG = 24
  if (t >= 98) return;
  const int g = sx - (sx / 24) * 24;
  __shared__ __align__(16) uint8_t Bs[32768];
  const int tid = threadIdx.x;
  const int wave = tid >> 6, lane = tid & 63;
  const long m0 = (long)t * 256;
  const int n0 = g << 6;
  // stage B: 64 cols x 512 K = 32 KB, linear (MX-B layout block)
  const uint8_t* bsrc = Bw + (long)n0 * 512;
  #pragma unroll
  for (int c = 0; c < 8; ++c)
    gload16(bsrc + c * 4096 + tid * 16, Bs + c * 4096 + tid * 16);
  // A: two 32-row panels per wave; MX-A layout
  const uint8_t* ab0 = A + (m0 + wave * 64) * 512 + lane * 32;
  const uint8_t* ab1 = ab0 + 16384;
  floatx16 acc[2][2] = {};
  __syncthreads();
  #pragma unroll
  for (int s = 0; s < 8; ++s) {
    const intx8 a0 = cat8(*(const intx4*)(ab0 + s * 2048), *(const intx4*)(ab0 + s * 2048 + 16));
    const intx8 a1 = cat8(*(const intx4*)(ab1 + s * 2048), *(const intx4*)(ab1 + s * 2048 + 16));
    const intx8 b0 = cat8(*(const intx4*)(Bs + s * 2048 + lane * 16),
                          *(const intx4*)(Bs + s * 2048 + 1024 + lane * 16));
    const intx8 b1 = cat8(*(const intx4*)(Bs + 16384 + s * 2048 + lane * 16),
                          *(const intx4*)(Bs + 16384 + s * 2048 + 1024 + lane * 16));
    acc[0][0] = mfma_mx(a0, b0, acc[0][0]);
    acc[0][1] = mfma_mx(a0, b1, acc[0][1]);
    acc[1][0] = mfma_mx(a1, b0, acc[1][0]);
    acc[1][1] = mfma_mx(a1, b1, acc[1][1]);
  }
  // ---- epilogue: 16 KB token-contiguous LDS image -> coalesced token-major stores ----
  __syncthreads();                 // all waves done reading Bs
  uint8_t* Ex = Bs;
  const int cp = lane & 31;
  const int hl = cp << 1;          // local col pair base 0..62 (even)
  const float2 b2 = *(const float2*)(bias + n0 + hl);
  const float qs = (n0 + hl < 512) ? QSCALE : 1.f;   // pair-uniform (hl even, 512 even)
  #pragma unroll
  for (int ri = 0; ri < 2; ++ri)
    #pragma unroll
    for (int q = 0; q < 16; ++q) {
      const int ml = wave * 64 + ri * 32 + 4 * (lane >> 5) + (q & 3) + 8 * (q >> 2);
      const float v0 = (acc[ri][0][q] + b2.x) * qs;
      const float v1 = (acc[ri][1][q] + b2.y) * qs;
      const int w = pk_fp8<false>(v0, v1, 0);
      *(uint16_t*)(Ex + ml * 64 + hl) = (uint16_t)(w & 0xffff);
    }
  __syncthreads();
  // 1024 16-B units -> QKV token-major: row = u>>2, chunk = u&3
  #pragma unroll
  for (int t2 = 0; t2 < 4; ++t2) {
    const int u = t2 * 256 + tid;
    const long gaddr = (m0 + (u >> 2)) * 1536 + n0 + ((u & 3) << 4);
    *(int4*)(outb + gaddr) = *(const int4*)(Ex + u * 16);
  }
}

// ---------- fc1: MX-scaled fp8 GEMM, 32x32x64, K=512 -> GELU -> Hb (16x16 frag, K2=2048) ----------
// R6-verified: LDS-exchange epilogue.
__global__ __launch_bounds__(256, 4)
void gemm_mx_fc1(const uint8_t* __restrict__ A, const uint8_t* __restrict__ Bw,
                 const float* __restrict__ bias, uint8_t* __restrict__ outb) {
  const int kx = blockIdx.x & 7;
  const int sx = blockIdx.x >> 3;
  const int t = (sx >> 5) * 8 + kx;     // NG = 32
  if (t >= 98) return;
  const int g = sx & 31;
  __shared__ __align__(16) uint8_t Bs[32768];
  const int tid = threadIdx.x;
  const int wave = tid >> 6, lane = tid & 63;
  const long m0 = (long)t * 256;
  const int n0 = g << 6;
  // stage B: 64 cols x 512 K = 32 KB, linear
  const uint8_t* bsrc = Bw + (long)n0 * 512;
  #pragma unroll
  for (int c = 0; c < 8; ++c)
    gload16(bsrc + c * 4096 + tid * 16, Bs + c * 4096 + tid * 16);
  // A: two 32-row panels per wave; MX layout => per slice s, lane reads 32 B at +s*2048+lane*32
  const uint8_t* ab0 = A + (m0 + wave * 64) * 512 + lane * 32;
  const uint8_t* ab1 = ab0 + 16384;
  floatx16 acc[2][2] = {};
  __syncthreads();
  #pragma unroll
  for (int s = 0; s < 8; ++s) {
    const intx8 a0 = cat8(*(const intx4*)(ab0 + s * 2048), *(const intx4*)(ab0 + s * 2048 + 16));
    const intx8 a1 = cat8(*(const intx4*)(ab1 + s * 2048), *(const intx4*)(ab1 + s * 2048 + 16));
    const intx8 b0 = cat8(*(const intx4*)(Bs + s * 2048 + lane * 16),
                          *(const intx4*)(Bs + s * 2048 + 1024 + lane * 16));
    const intx8 b1 = cat8(*(const intx4*)(Bs + 16384 + s * 2048 + lane * 16),
                          *(const intx4*)(Bs + 16384 + s * 2048 + 1024 + lane * 16));
    acc[0][0] = mfma_mx(a0, b0, acc[0][0]);
    acc[0][1] = mfma_mx(a0, b1, acc[0][1]);
    acc[1][0] = mfma_mx(a1, b0, acc[1][0]);
    acc[1][1] = mfma_mx(a1, b1, acc[1][1]);
  }
  // ---- epilogue via LDS exchange (compact 16 KB image -> coalesced dwordx4 stores) ----
  __syncthreads();                 // all waves done reading Bs
  uint8_t* Ex = Bs;
  const int cp = lane & 31;
  const int hl = cp << 1;          // local h pair base 0..62
  const float2 b2 = *(const float2*)(bias + n0 + hl);
  const int hoff = ((hl >> 3) << 4) + (hl & 7);   // o*16 + e
  #pragma unroll
  for (int ri = 0; ri < 2; ++ri)
    #pragma unroll
    for (int q = 0; q < 16; ++q) {
      const int ml = wave * 64 + ri * 32 + 4 * (lane >> 5) + (q & 3) + 8 * (q >> 2);
      const float v0 = fast_gelu(acc[ri][0][q] + b2.x);
      const float v1 = fast_gelu(acc[ri][1][q] + b2.y);
      const int w = pk_fp8<false>(v0, v1, 0);
      const int laddr = ((ml >> 4) << 10) + (((ml & 15) >> 1) << 7) + ((ml & 1) << 3) + hoff;
      *(uint16_t*)(Ex + laddr) = (uint16_t)(w & 0xffff);
    }
  __syncthreads();
  // 1024 16-B units -> Hb: u = p*64 + j2*8 + o
  #pragma unroll
  for (int t2 = 0; t2 < 4; ++t2) {
    const int u = t2 * 256 + tid;
    const long gaddr = (m0 + ((u >> 6) << 4)) * 2048 + (((long)(n0 >> 3) + (u & 7)) << 7)
                     + (((u >> 3) & 7) << 4);
    *(int4*)(outb + gaddr) = *(const int4*)(Ex + u * 16);
  }
}

// ---------- BM table: bias+mask+padding in MFMA C-layout order ----------
__global__ __launch_bounds__(256)
void bm_build(const float* __restrict__ rel_bias, float* __restrict__ BM) {
  const int hw = blockIdx.x;           // head*4 + wpos
  const int head = hw >> 2, wpos = hw & 3;
  const int wi = wpos >> 1, wj = wpos & 1;
  for (int k = 0; k < 4; ++k) {
    const int idx = k * 256 + threadIdx.x;   // tile*64 + lane
    const int tile = idx >> 6, l = idx & 63;
    const int qi = tile >> 2, ti = tile & 3;
    const int n = l & 15, g = l >> 4;
    const int query = qi * 16 + n;
    const int qy = query / 7, qx = query - qy * 7;
    const int hh = wi * 7 + qy, ww = wj * 7 + qx;
    const int ri = (hh < 7 ? 0 : (hh < 11 ? 1 : 2)) * 3 + (ww < 7 ? 0 : (ww < 11 ? 1 : 2));
    float4 ov;
    float vv[4];
    #pragma unroll
    for (int r = 0; r < 4; ++r) {
      const int key = ti * 16 + g * 4 + r;
      float v;
      if (query >= 49 || key >= 49) {
        v = -3.0e38f;
      } else {
        const int ky = key / 7, kx = key - ky * 7;
        const int bidx = (qy - ky + 6) * 13 + (qx - kx + 6);
        const int h2 = wi * 7 + ky, w2 = wj * 7 + kx;
        const int rj = (h2 < 7 ? 0 : (h2 < 11 ? 1 : 2)) * 3 + (w2 < 7 ? 0 : (w2 < 11 ? 1 : 2));
        v = rel_bias[bidx * 16 + head] + ((ri != rj) ? -100.f : 0.f);
      }
      vv[r] = v;
    }
    ov.x = vv[0]; ov.y = vv[1]; ov.z = vv[2]; ov.w = vv[3];
    *(float4*)(BM + ((long)(hw * 16 + tile) << 8) + l * 4) = ov;
  }
}

// ---------- 4x4 byte transpose ----------
__device__ __forceinline__ void tr4(const uint32_t d[4], uint32_t o[4]) {
  #pragma unroll
  for (int c = 0; c < 4; ++c)
    o[c] = ((d[0] >> (8 * c)) & 0xffu) | (((d[1] >> (8 * c)) & 0xffu) << 8)
         | (((d[2] >> (8 * c)) & 0xffu) << 16) | (((d[3] >> (8 * c)) & 0xffu) << 24);
}

// ---------- MFMA windowed attention: one wave per (window, head); AT written frag-major ----------
__global__ __launch_bounds__(256)
void attn_mfma(const uint8_t* __restrict__ QKV, const float* __restrict__ BM,
               uint8_t* __restrict__ AT) {
  __shared__ uint8_t lds[4][9984];   // per-wave: Pb 64x72, Vt 32x72, Ot 64x48
  const int wave = threadIdx.x >> 6, lane = threadIdx.x & 63;
  const int n = lane & 15, g = lane >> 4;
  const int gw = blockIdx.x * 4 + wave;
  const int wd = gw >> 4, head = gw & 15;
  const int b = wd >> 2, wpos = wd & 3;
  const int wi = wpos >> 1, wj = wpos & 1;
  uint8_t* Pb = lds[wave];
  uint8_t* Vt = lds[wave] + 4608;
  uint8_t* Ot = lds[wave] + 6912;
  const long base = (long)b * 196 * 1536;
  auto tok = [&](int slot) -> int {
    const int ty = slot / 7, tx = slot - ty * 7;
    int h = wi * 7 + ty + 3; if (h >= 14) h -= 14;
    int w = wj * 7 + tx + 3; if (w >= 14) w -= 14;
    return h * 14 + w;
  };
  long Ak[4], Bq[4];
  #pragma unroll
  for (int t4 = 0; t4 < 4; ++t4) {
    int slot = t4 * 16 + n; if (slot > 48) slot = 48;
    const long tb = base + (long)tok(slot) * 1536 + head * 32 + g * 8;
    Bq[t4] = *(const long*)(QKV + tb);          // Q rows (B operand)
    Ak[t4] = *(const long*)(QKV + tb + 512);    // K rows (A operand)
  }
  #pragma unroll
  for (int bb2 = 0; bb2 < 2; ++bb2) {
    const int blk = lane + bb2 * 64;
    const int dq = blk >> 4, tq = blk & 15;
    uint32_t d4[4], o4[4];
    #pragma unroll
    for (int r = 0; r < 4; ++r) {
      int slot = tq * 4 + r; if (slot > 48) slot = 48;
      d4[r] = *(const uint32_t*)(QKV + base + (long)tok(slot) * 1536 + 1024 + head * 32 + dq * 4);
    }
    tr4(d4, o4);
    #pragma unroll
    for (int c = 0; c < 4; ++c)
      *(uint32_t*)(Vt + (dq * 4 + c) * 72 + tq * 4) = o4[c];
  }
  floatx4 acc[4][4];
  const float* bmw = BM + ((long)(head * 4 + wpos) << 12) + lane * 4;
  #pragma unroll
  for (int qi = 0; qi < 4; ++qi)
    #pragma unroll
    for (int ti = 0; ti < 4; ++ti) {
      const float4 bv = *(const float4*)(bmw + ((qi * 4 + ti) << 8));
      acc[qi][ti][0] = bv.x; acc[qi][ti][1] = bv.y;
      acc[qi][ti][2] = bv.z; acc[qi][ti][3] = bv.w;
    }
  #pragma unroll
  for (int qi = 0; qi < 4; ++qi)
    #pragma unroll
    for (int ti = 0; ti < 4; ++ti)
      acc[qi][ti] = __builtin_amdgcn_mfma_f32_16x16x32_fp8_fp8(Ak[ti], Bq[qi], acc[qi][ti], 0, 0, 0);
  #pragma unroll
  for (int qi = 0; qi < 4; ++qi) {
    float mx = -3.0e38f;
    #pragma unroll
    for (int ti = 0; ti < 4; ++ti)
      #pragma unroll
      for (int r = 0; r < 4; ++r) mx = fmaxf(mx, acc[qi][ti][r]);
    mx = fmaxf(mx, __shfl_xor(mx, 16));
    mx = fmaxf(mx, __shfl_xor(mx, 32));
    float sum = 0.f;
    #pragma unroll
    for (int ti = 0; ti < 4; ++ti)
      #pragma unroll
      for (int r = 0; r < 4; ++r) {
        const float e = __expf(acc[qi][ti][r] - mx);
        acc[qi][ti][r] = e; sum += e;
      }
    sum += __shfl_xor(sum, 16);
    sum += __shfl_xor(sum, 32);
    const float inv = 1.f / sum;
    #pragma unroll
    for (int ti = 0; ti < 4; ++ti) {
      const int pw = pk_fp8x4(acc[qi][ti][0] * inv, acc[qi][ti][1] * inv,
                              acc[qi][ti][2] * inv, acc[qi][ti][3] * inv);
      *(uint32_t*)(Pb + (qi * 16 + n) * 72 + ti * 16 + g * 4) = pw;
    }
  }
  asm volatile("s_waitcnt lgkmcnt(0)" ::: "memory");
  long Bv[2][2];
  #pragma unroll
  for (int ni = 0; ni < 2; ++ni)
    #pragma unroll
    for (int s = 0; s < 2; ++s)
      Bv[ni][s] = *(const long*)(Vt + (ni * 16 + n) * 72 + s * 32 + g * 8);
  floatx4 o[4][2] = {};
  #pragma unroll
  for (int qi = 0; qi < 4; ++qi)
    #pragma unroll
    for (int s = 0; s < 2; ++s) {
      const long Ap = *(const long*)(Pb + (qi * 16 + n) * 72 + s * 32 + g * 8);
      #pragma unroll
      for (int ni = 0; ni < 2; ++ni)
        o[qi][ni] = __builtin_amdgcn_mfma_f32_16x16x32_fp8_fp8(Ap, Bv[ni][s], o[qi][ni], 0, 0, 0);
    }
  #pragma unroll
  for (int qi = 0; qi < 4; ++qi)
    #pragma unroll
    for (int ni = 0; ni < 2; ++ni)
      #pragma unroll
      for (int r = 0; r < 4; ++r)
        Ot[(qi * 16 + g * 4 + r) * 48 + ni * 16 + n] =
            (uint8_t)(pk_fp8<false>(o[qi][ni][r], 0.f, 0) & 0xff);
  asm volatile("s_waitcnt lgkmcnt(0)" ::: "memory");
  if (lane < 49) {
    const int m = b * 196 + tok(lane);
    uint8_t* opb = AT + (long)(m & ~15) * 512 + ((m & 15) << 3);
    #pragma unroll
    for (int d8 = 0; d8 < 4; ++d8)
      *(long*)(opb + (head * 4 + d8) * 128) = *(const long*)(Ot + lane * 48 + d8 * 8);
  }
}

extern "C" void kernel_launch(void* const* d_in, const int* in_sizes, int n_in,
                              void* d_out, int out_size, void* d_ws, size_t ws_size,
                              hipStream_t stream) {
  const float* x      = (const float*)d_in[0];
  const float* ln1_w  = (const float*)d_in[1];
  const float* ln1_b  = (const float*)d_in[2];
  const float* qkv_w  = (const float*)d_in[3];
  const float* qkv_b  = (const float*)d_in[4];
  const float* relb   = (const float*)d_in[5];
  const float* proj_w = (const float*)d_in[6];
  const float* proj_b = (const float*)d_in[7];
  const float* gamma1 = (const float*)d_in[8];
  const float* ln2_w  = (const float*)d_in[9];
  const float* ln2_b  = (const float*)d_in[10];
  const float* fc1_w  = (const float*)d_in[11];
  const float* fc1_b  = (const float*)d_in[12];
  const float* fc2_w  = (const float*)d_in[13];
  const float* fc2_b  = (const float*)d_in[14];
  const float* gamma2 = (const float*)d_in[15];
  float* out = (float*)d_out;
  char* ws = (char*)d_ws;

  float*    mu1 = (float*)(ws + 0);
  float*    rs1 = (float*)(ws + 100352);
  float*    S1  = (float*)(ws + 200704);      // LN2 raw sum
  float*    S2  = (float*)(ws + 301056);      // LN2 raw sumsq
  uint8_t*  Wq  = (uint8_t*)(ws + 401408);    //   786,432 B (MX-B layout)
  uint8_t*  Wp  = (uint8_t*)(ws + 1187840);   //   262,144 B frag-major
  uint8_t*  W1  = (uint8_t*)(ws + 1449984);   // 1,048,576 B (MX-B layout)
  uint8_t*  W2  = (uint8_t*)(ws + 2498560);   // 1,048,576 B frag-major
  float*    BMt = (float*)  (ws + 3547136);   // 1,048,576 B bias+mask table
  uint8_t*  Afp = (uint8_t*)(ws + 4595712);   // 12,845,056 B tokens (MX-A: LN1, later LN2)
  uint16_t* X1b = (uint16_t*)(ws + 68820992); // 25,690,112 B token-major bf16
  uint8_t*  QKV = (uint8_t*)(ws + 120201216); // 38,535,168 B token-major fp8
  uint8_t*  AT  = (uint8_t*)(ws + 158736384); // 12,845,056 B frag-major fp8
  uint8_t*  Hb  = (uint8_t*)(ws + 120201216); // 51,380,224 B 16x16 frag-major, overlaps dead QKV+AT

  // zero LN2 sum buffers (atomics accumulate during proj epilogue)
  hipMemsetAsync(ws + 200704, 0, 200704, stream);

  // weights -> fp8 (MX-B for qkv/fc1; 16x16 frag for proj/fc2), BM table
  cvt_frag_mx512<<<768,  256, 0, stream>>>(qkv_w, Wq, 196608);
  cvt_frag<512> <<<256,  256, 0, stream>>>(proj_w, Wp, 65536);
  cvt_frag_mx512<<<1024, 256, 0, stream>>>(fc1_w, W1, 262144);
  cvt_frag<2048><<<1024, 256, 0, stream>>>(fc2_w, W2, 262144);
  bm_build<<<64, 256, 0, stream>>>(relb, BMt);

  // LN1 -> MX-A fp8 tokens
  ln_stats_nchw<<<392, 256, 0, stream>>>(x, mu1, rs1);
  ln1_apply<<<4096, 256, 0, stream>>>(x, mu1, rs1, ln1_w, ln1_b, Afp);

  // qkv: MX 32x32x64 GEMM (q pre-scaled) -> token-major QKV: grid 8*13*24 = 2496
  gemm_mx_qkv<<<2496, 256, 0, stream>>>(Afp, Wq, qkv_b, QKV);

  // shifted-window attention (MFMA), frag-major AT out
  attn_mfma<<<2048, 256, 0, stream>>>(QKV, BMt, AT);

  // proj GEMM: X1b(bf16) = x(NCHW) + g1*(out+b); fused LN2 stats: T=98, NG=8 -> 832
  gemm_bl<4, 512, 1, 8, 98, 2><<<832, 256, 0, stream>>>(AT, Wp, proj_b, x, nullptr, gamma1, nullptr, nullptr, X1b, S1, S2, 512);

  // LN2 apply -> MX-A fp8 tokens
  ln2_panel<<<1568, 256, 0, stream>>>(X1b, S1, S2, ln2_w, ln2_b, Afp);

  // fc1: MX-scaled 32x32x64 GEMM + GELU -> Hb (16x16 frag): grid 8*13*32 = 3328
  gemm_mx_fc1<<<3328, 256, 0, stream>>>(Afp, W1, fc1_b, Hb);

  // fc2 (T=196, NG=8 -> 1600) -> NCHW out via LDS exchange; A prefetch depth 8
  gemm_bl<2, 2048, 3, 8, 196, 8><<<1600, 256, 0, stream>>>(Hb, W2, fc2_b, nullptr, X1b, gamma2, nullptr, out, nullptr, nullptr, nullptr, 512);
}

// Round 12
// 362.668 us; speedup vs baseline: 1.0208x; 1.0208x over previous
//
#include <hip/hip_runtime.h>
#include <cmath>
#include <cstdint>

typedef float floatx4 __attribute__((ext_vector_type(4)));
typedef float floatx16 __attribute__((ext_vector_type(16)));
typedef int   intx4   __attribute__((ext_vector_type(4)));
typedef int   intx8   __attribute__((ext_vector_type(8)));

#define EPS_ 1e-5f
#define QSCALE 0.17677669529663689f

// ---------- async global->LDS (16B per lane) ----------
__device__ __forceinline__ void gload16(const uint8_t* g, uint8_t* l) {
  __builtin_amdgcn_global_load_lds(
      (const __attribute__((address_space(1))) void*)g,
      (__attribute__((address_space(3))) void*)l, 16, 0, 0);
}

// ---------- fp8 e4m3 pack (word-select must be an immediate) ----------
template<bool HI>
__device__ __forceinline__ int pk_fp8(float a, float b, int old) {
  return __builtin_amdgcn_cvt_pk_fp8_f32(a, b, old, HI);
}
__device__ __forceinline__ int pk_fp8x4(float v0, float v1, float v2, float v3) {
  int w = pk_fp8<false>(v0, v1, 0);
  return pk_fp8<true>(v2, v3, w);
}

// ---------- bf16 helpers (RNE) ----------
__device__ __forceinline__ uint16_t f2bf(float f) {
  uint32_t u = __float_as_uint(f);
  return (uint16_t)((u + 0x7fffu + ((u >> 16) & 1u)) >> 16);
}
__device__ __forceinline__ float bf2f(uint16_t h) {
  return __uint_as_float(((uint32_t)h) << 16);
}

// ---------- fast GELU: x*sigmoid(1.702x) (error << fp8 quant; branch scaled by 1e-6) ----------
__device__ __forceinline__ float fast_gelu(float v) {
  const float t = __expf(-1.702f * v);
  return v * __builtin_amdgcn_rcpf(1.f + t);
}

// ---------- MX-scaled fp8 MFMA (unity scales: E8M0 127 = 2^0) ----------
__device__ __forceinline__ intx8 cat8(intx4 a, intx4 b) {
  return __builtin_shufflevector(a, b, 0, 1, 2, 3, 4, 5, 6, 7);
}
__device__ __forceinline__ floatx16 mfma_mx(intx8 a, intx8 b, floatx16 c) {
  return __builtin_amdgcn_mfma_scale_f32_32x32x64_f8f6f4(
      a, b, c, 0, 0, 0, 0x7F7F7F7F, 0, 0x7F7F7F7F);
}

// 16x16 fragment-major layout (proj/fc2 operands):
//   addr(m, k) = (m & ~15)*K + (k>>3)*128 + (m & 15)*8 + (k & 7)
// MX 32x32 A layout (qkv/fc1 A tokens): addr(m,k) = (m>>5)*32*K + (k>>5)*1024 + (m&31)*32 + (k&31)
// MX 32x32 B layout (Wq/W1, col-pair permuted): lane holds cols n0+2*(lane&31)+{0,1}

// ---------- fp32 weights -> fp8 frag-major 16x16 (col-permuted) ----------
template<int K>
__global__ void cvt_frag(const float* __restrict__ s, uint8_t* __restrict__ d, int n4) {
  const int i = blockIdx.x * 256 + threadIdx.x;
  if (i >= n4) return;
  const int kq = K >> 2;
  const int n = i / kq;
  const int k = (i - n * kq) << 2;
  const float4 v = ((const float4*)s)[i];
  const int panel = ((n >> 6) << 2) + (n & 3);
  const int lm = (n >> 2) & 15;
  const long addr = (long)panel * (16 * K) + ((k >> 3) << 7) + (lm << 3) + (k & 4);
  *(int*)(d + addr) = pk_fp8x4(v.x, v.y, v.z, v.w);
}

// ---------- fp32 weights -> fp8 MX 32x32 B layout (K=512; any N multiple of 64) ----------
__global__ void cvt_frag_mx512(const float* __restrict__ s, uint8_t* __restrict__ d, int n4) {
  const int i = blockIdx.x * 256 + threadIdx.x;
  if (i >= n4) return;
  const int n = i >> 7;               // out-channel (col), K/4 = 128
  const int k = (i & 127) << 2;
  const float4 v = ((const float4*)s)[i];
  const long addr = (long)(n >> 6) * 32768 + (n & 1) * 16384 + ((k >> 6) << 11)
                  + (((k >> 4) & 1) << 10)
                  + ((((k >> 5) & 1) << 5) + ((n & 63) >> 1)) * 16 + (k & 15);
  *(int*)(d + addr) = pk_fp8x4(v.x, v.y, v.z, v.w);
}

// ---------- LN1 stats over C for NCHW input ----------
__global__ __launch_bounds__(256)
void ln_stats_nchw(const float* __restrict__ x, float* __restrict__ mu, float* __restrict__ rs) {
  const int tl = threadIdx.x & 63;
  const int wv = threadIdx.x >> 6;
  const int t = blockIdx.x * 64 + tl;       // token = b*196 + p
  const int b = t / 196;
  const int p = t - b * 196;
  const float* xp = x + (long)b * 100352 + p;
  float s = 0.f, ss = 0.f;
  const int cbeg = wv * 128;
  for (int c = cbeg; c < cbeg + 128; ++c) {
    const float v = xp[(long)c * 196];
    s += v; ss += v * v;
  }
  __shared__ float sb[4][64], qb[4][64];
  sb[wv][tl] = s; qb[wv][tl] = ss;
  __syncthreads();
  if (wv == 0) {
    s  = sb[0][tl] + sb[1][tl] + sb[2][tl] + sb[3][tl];
    ss = qb[0][tl] + qb[1][tl] + qb[2][tl] + qb[3][tl];
    const float m = s * (1.f / 512.f);
    const float var = ss * (1.f / 512.f) - m * m;
    mu[t] = m;
    rs[t] = rsqrtf(var + EPS_);
  }
}

// ---------- LN1 apply: NCHW -> MX 32x32 A-layout fp8 tokens (feeds MX qkv) ----------
__global__ __launch_bounds__(256)
void ln1_apply(const float* __restrict__ x, const float* __restrict__ mu, const float* __restrict__ rs,
               const float* __restrict__ w, const float* __restrict__ bb, uint8_t* __restrict__ A) {
  __shared__ float tile[64][53];
  const int bid = blockIdx.x;
  const int ct = bid & 7;
  const int pt = (bid >> 3) & 3;
  const int b = bid >> 5;
  const int p0 = pt * 49, c0 = ct * 64;
  const long xbase = (long)b * 100352;
  for (int idx = threadIdx.x; idx < 3136; idx += 256) {
    const int cl = idx / 49;
    const int pl = idx - cl * 49;
    tile[cl][pl] = x[xbase + (long)(c0 + cl) * 196 + p0 + pl];
  }
  __syncthreads();
  const int tbase = b * 196 + p0;
  for (int idx = threadIdx.x; idx < 784; idx += 256) {
    const int pl = idx >> 4;                // 0..48
    const int cq = (idx & 15) << 2;         // 0..60 step 4
    const int t = tbase + pl;
    const int c = c0 + cq;
    const float m = mu[t], rr = rs[t];
    const float v0 = (tile[cq + 0][pl] - m) * rr * w[c + 0] + bb[c + 0];
    const float v1 = (tile[cq + 1][pl] - m) * rr * w[c + 1] + bb[c + 1];
    const float v2 = (tile[cq + 2][pl] - m) * rr * w[c + 2] + bb[c + 2];
    const float v3 = (tile[cq + 3][pl] - m) * rr * w[c + 3] + bb[c + 3];
    // MX A layout: (t>>5)*16384 + (c>>5)*1024 + (t&31)*32 + (c&31)
    const long addr = (long)(t >> 5) * 16384 + ((c >> 5) << 10) + ((t & 31) << 5) + (c & 31);
    *(int*)(A + addr) = pk_fp8x4(v0, v1, v2, v3);
  }
}

// ---------- LN2: one block per 16-token panel; X1 bf16 -> MX 32x32 A-layout fp8 ----------
__global__ __launch_bounds__(256)
void ln2_panel(const uint16_t* __restrict__ Xb, const float* __restrict__ S1,
               const float* __restrict__ S2, const float* __restrict__ w,
               const float* __restrict__ bb, uint8_t* __restrict__ Z) {
  __shared__ float xs[16 * 516];
  const int p = blockIdx.x;
  const int t0 = p * 16;
  for (int idx = threadIdx.x; idx < 1024; idx += 256) {
    const int tl = idx >> 6;                 // token 0..15
    const int c8 = (idx & 63) << 3;          // 0..504 step 8
    const uint4 raw = *(const uint4*)(Xb + ((long)(t0 + tl) << 9) + c8);
    float* xr = xs + tl * 516 + c8;
    xr[0] = bf2f((uint16_t)(raw.x & 0xffff)); xr[1] = bf2f((uint16_t)(raw.x >> 16));
    xr[2] = bf2f((uint16_t)(raw.y & 0xffff)); xr[3] = bf2f((uint16_t)(raw.y >> 16));
    xr[4] = bf2f((uint16_t)(raw.z & 0xffff)); xr[5] = bf2f((uint16_t)(raw.z >> 16));
    xr[6] = bf2f((uint16_t)(raw.w & 0xffff)); xr[7] = bf2f((uint16_t)(raw.w >> 16));
  }
  __syncthreads();
  for (int e = threadIdx.x; e < 2048; e += 256) {
    const int tl = e >> 7;             // token 0..15
    const int c  = (e & 127) << 2;     // channel 0..508 step 4
    const int t = t0 + tl;
    const float m = S1[t] * (1.f / 512.f);
    const float var = S2[t] * (1.f / 512.f) - m * m;
    const float r = rsqrtf(var + EPS_);
    const float* xr = xs + tl * 516 + c;
    const float v0 = (xr[0] - m) * r * w[c + 0] + bb[c + 0];
    const float v1 = (xr[1] - m) * r * w[c + 1] + bb[c + 1];
    const float v2 = (xr[2] - m) * r * w[c + 2] + bb[c + 2];
    const float v3 = (xr[3] - m) * r * w[c + 3] + bb[c + 3];
    // MX A layout: (t>>5)*16384 + (c>>5)*1024 + (t&31)*32 + (c&31)
    const long addr = (long)(t >> 5) * 16384 + ((c >> 5) << 10) + ((t & 31) << 5) + (c & 31);
    *(int*)(Z + addr) = pk_fp8x4(v0, v1, v2, v3);
  }
}

// ---------- fp8 16x16 MFMA GEMM (R1-verified structure): B LDS, A direct-global ----------
// 4 waves x (MI*16 rows) x 64 cols; A prefetch dist 2; XCD-swizzled grid.
// EPI 1: proj -> bf16 X1 = x + g1*(acc+b); fused LN2 raw-sum atomics
// EPI 3: fc2 -> f32 NCHW via LDS exchange (MI=2: 128 rows)
// (R11's PD=8 A-prefetch was a verified null: compiler folds it back — VGPR/dur unchanged.)
template<int MI, int K, int EPI, int NG, int T>
__global__ __launch_bounds__(256, 4)
void gemm_bl(const uint8_t* __restrict__ A, const uint8_t* __restrict__ Bw,
             const float* __restrict__ bias, const float* __restrict__ res,
             const uint16_t* __restrict__ resb, const float* __restrict__ gamma,
             uint8_t* __restrict__ outb, float* __restrict__ outf,
             uint16_t* __restrict__ outh, float* __restrict__ S1, float* __restrict__ S2,
             const int N) {
  const int kx = blockIdx.x & 7;
  const int sx = blockIdx.x >> 3;
  const int t = (sx / NG) * 8 + kx;
  if (t >= T) return;
  const int g = sx - (sx / NG) * NG;        // 64-col group
  __shared__ __align__(16) uint8_t Bs[(EPI == 3) ? 33280 : 32768];
  const int tid = threadIdx.x;
  const int wave = tid >> 6, lane = tid & 63;
  const int lm = lane & 15, lq = lane >> 4;
  const long m0 = (long)t * (MI * 64);
  const long n0 = (long)g << 6;
  const uint8_t* abase = A + (m0 + wave * MI * 16) * (long)K + (lane << 3);
  floatx4 acc[MI][4] = {};
  constexpr int NKS = K / 32;
  long aP0[MI], aP1[MI];
  #pragma unroll
  for (int i = 0; i < MI; ++i) {
    aP0[i] = *(const long*)(abase + (long)i * 16 * K);
    aP1[i] = *(const long*)(abase + (long)i * 16 * K + 512);
  }
  #pragma unroll
  for (int ph = 0; ph < K / 512; ++ph) {
    const uint8_t* bsrc = Bw + n0 * K + ph * 8192;
    #pragma unroll
    for (int j = 0; j < 4; ++j)
      #pragma unroll
      for (int c = 0; c < 2; ++c)
        gload16(bsrc + (long)j * 16 * K + c * 4096 + tid * 16,
                Bs + j * 8192 + c * 4096 + tid * 16);
    __syncthreads();
    #pragma unroll
    for (int ksl = 0; ksl < 16; ++ksl) {
      const int sg = ph * 16 + ksl;
      long aC[MI];
      #pragma unroll
      for (int i = 0; i < MI; ++i) aC[i] = (ksl & 1) ? aP1[i] : aP0[i];
      if (sg + 2 < NKS) {
        #pragma unroll
        for (int i = 0; i < MI; ++i) {
          const long v = *(const long*)(abase + (long)i * 16 * K + (long)(sg + 2) * 512);
          if (ksl & 1) aP1[i] = v; else aP0[i] = v;
        }
      }
      long bf[4];
      #pragma unroll
      for (int j = 0; j < 4; ++j)
        bf[j] = *(const long*)(Bs + j * 8192 + ksl * 512 + (lane << 3));
      __builtin_amdgcn_s_setprio(1);
      #pragma unroll
      for (int i = 0; i < MI; ++i)
        #pragma unroll
        for (int j = 0; j < 4; ++j)
          acc[i][j] = __builtin_amdgcn_mfma_f32_16x16x32_fp8_fp8(aC[i], bf[j], acc[i][j], 0, 0, 0);
      __builtin_amdgcn_s_setprio(0);
    }
    if (K / 512 > 1 && ph + 1 < K / 512) __syncthreads();
  }
  const int cb = (g << 6) + (lm << 2);
  const float4 b4 = *(const float4*)(bias + cb);
  float4 g4 = make_float4(0.f, 0.f, 0.f, 0.f);
  if (EPI == 1 || EPI == 3) g4 = *(const float4*)(gamma + cb);
  if (EPI != 3) {
    #pragma unroll
    for (int i = 0; i < MI; ++i) {
      #pragma unroll
      for (int r = 0; r < 4; ++r) {
        const long rowg = m0 + wave * MI * 16 + i * 16 + lq * 4 + r;
        float v0 = acc[i][0][r] + b4.x;
        float v1 = acc[i][1][r] + b4.y;
        float v2 = acc[i][2][r] + b4.z;
        float v3 = acc[i][3][r] + b4.w;
        {   // EPI 1
          const unsigned rg = (unsigned)rowg;
          const unsigned bi = rg / 196u;
          const unsigned p = rg - bi * 196u;
          const float* xr = res + (long)bi * 100352 + p;
          const float o0 = xr[(long)(cb + 0) * 196] + g4.x * v0;
          const float o1 = xr[(long)(cb + 1) * 196] + g4.y * v1;
          const float o2 = xr[(long)(cb + 2) * 196] + g4.z * v2;
          const float o3 = xr[(long)(cb + 3) * 196] + g4.w * v3;
          ushort4 hv;
          hv.x = f2bf(o0); hv.y = f2bf(o1); hv.z = f2bf(o2); hv.w = f2bf(o3);
          *(ushort4*)(outh + rowg * 512 + cb) = hv;
          const float q0 = bf2f(hv.x), q1 = bf2f(hv.y), q2 = bf2f(hv.z), q3 = bf2f(hv.w);
          float s = q0 + q1 + q2 + q3;
          float ss = q0 * q0 + q1 * q1 + q2 * q2 + q3 * q3;
          s += __shfl_xor(s, 1);  ss += __shfl_xor(ss, 1);
          s += __shfl_xor(s, 2);  ss += __shfl_xor(ss, 2);
          s += __shfl_xor(s, 4);  ss += __shfl_xor(ss, 4);
          s += __shfl_xor(s, 8);  ss += __shfl_xor(ss, 8);
          if (lm == 0) {
            atomicAdd(S1 + rowg, s);
            atomicAdd(S2 + rowg, ss);
          }
        }
      }
    }
  } else {
    // EPI 3 (MI=2): 128-row tile -> NCHW via LDS exchange, coalesced (stride 129)
    float* Tx = (float*)Bs;
    __syncthreads();
    #pragma unroll
    for (int i = 0; i < MI; ++i) {
      #pragma unroll
      for (int r = 0; r < 4; ++r) {
        const long rowg = m0 + wave * MI * 16 + i * 16 + lq * 4 + r;
        const int rl = (int)(rowg - m0);   // 0..127
        const ushort4 rb = *(const ushort4*)(resb + rowg * 512 + cb);
        Tx[(lm * 4 + 0) * 129 + rl] = bf2f(rb.x) + g4.x * (acc[i][0][r] + b4.x);
        Tx[(lm * 4 + 1) * 129 + rl] = bf2f(rb.y) + g4.y * (acc[i][1][r] + b4.y);
        Tx[(lm * 4 + 2) * 129 + rl] = bf2f(rb.z) + g4.z * (acc[i][2][r] + b4.z);
        Tx[(lm * 4 + 3) * 129 + rl] = bf2f(rb.w) + g4.w * (acc[i][3][r] + b4.w);
      }
    }
    __syncthreads();
    #pragma unroll
    for (int t2 = 0; t2 < 32; ++t2) {
      const int idx = t2 * 256 + tid;
      const int rl = idx & 127;
      const int ch = idx >> 7;
      const unsigned m = (unsigned)(m0 + rl);
      const unsigned bi = m / 196u;
      const unsigned p = m - bi * 196u;
      outf[(long)bi * 100352 + (long)(n0 + ch) * 196 + p] = Tx[ch * 129 + rl];
    }
  }
}

// ---------- qkv: MX-scaled fp8 GEMM, 32x32x64, K=512 -> fp8 token-major QKV ----------
// R10-verified: token-contiguous 16 KB LDS image -> coalesced token-major stores.
__global__ __launch_bounds__(256, 4)
void gemm_mx_qkv(const uint8_t* __restrict__ A, const uint8_t* __restrict__ Bw,
                 const float* __restrict__ bias, uint8_t* __restrict__ outb) {
  const int kx = blockIdx.x & 7;
  const int sx = blockIdx.x >> 3;
  const int t = (sx / 24) * 8 + kx;     // NG = 24
  if (t >= 98) return;
  const int g = sx - (sx / 24) * 24;
  __shared__ __align__(16) uint8_t Bs[32768];
  const int tid = threadIdx.x;
  const int wave = tid >> 6, lane = tid & 63;
  const long m0 = (long)t * 256;
  const int n0 = g << 6;
  // stage B: 64 cols x 512 K = 32 KB, linear (MX-B layout block)
  const uint8_t* bsrc = Bw + (long)n0 * 512;
  #pragma unroll
  for (int c = 0; c < 8; ++c)
    gload16(bsrc + c * 4096 + tid * 16, Bs + c * 4096 + tid * 16);
  // A: two 32-row panels per wave; MX-A layout
  const uint8_t* ab0 = A + (m0 + wave * 64) * 512 + lane * 32;
  const uint8_t* ab1 = ab0 + 16384;
  floatx16 acc[2][2] = {};
  __syncthreads();
  #pragma unroll
  for (int s = 0; s < 8; ++s) {
    const intx8 a0 = cat8(*(const intx4*)(ab0 + s * 2048), *(const intx4*)(ab0 + s * 2048 + 16));
    const intx8 a1 = cat8(*(const intx4*)(ab1 + s * 2048), *(const intx4*)(ab1 + s * 2048 + 16));
    const intx8 b0 = cat8(*(const intx4*)(Bs + s * 2048 + lane * 16),
                          *(const intx4*)(Bs + s * 2048 + 1024 + lane * 16));
    const intx8 b1 = cat8(*(const intx4*)(Bs + 16384 + s * 2048 + lane * 16),
                          *(const intx4*)(Bs + 16384 + s * 2048 + 1024 + lane * 16));
    acc[0][0] = mfma_mx(a0, b0, acc[0][0]);
    acc[0][1] = mfma_mx(a0, b1, acc[0][1]);
    acc[1][0] = mfma_mx(a1, b0, acc[1][0]);
    acc[1][1] = mfma_mx(a1, b1, acc[1][1]);
  }
  // ---- epilogue: 16 KB token-contiguous LDS image -> coalesced token-major stores ----
  __syncthreads();                 // all waves done reading Bs
  uint8_t* Ex = Bs;
  const int cp = lane & 31;
  const int hl = cp << 1;          // local col pair base 0..62 (even)
  const float2 b2 = *(const float2*)(bias + n0 + hl);
  const float qs = (n0 + hl < 512) ? QSCALE : 1.f;   // pair-uniform (hl even, 512 even)
  #pragma unroll
  for (int ri = 0; ri < 2; ++ri)
    #pragma unroll
    for (int q = 0; q < 16; ++q) {
      const int ml = wave * 64 + ri * 32 + 4 * (lane >> 5) + (q & 3) + 8 * (q >> 2);
      const float v0 = (acc[ri][0][q] + b2.x) * qs;
      const float v1 = (acc[ri][1][q] + b2.y) * qs;
      const int w = pk_fp8<false>(v0, v1, 0);
      *(uint16_t*)(Ex + ml * 64 + hl) = (uint16_t)(w & 0xffff);
    }
  __syncthreads();
  // 1024 16-B units -> QKV token-major: row = u>>2, chunk = u&3
  #pragma unroll
  for (int t2 = 0; t2 < 4; ++t2) {
    const int u = t2 * 256 + tid;
    const long gaddr = (m0 + (u >> 2)) * 1536 + n0 + ((u & 3) << 4);
    *(int4*)(outb + gaddr) = *(const int4*)(Ex + u * 16);
  }
}

// ---------- fc1: MX-scaled fp8 GEMM, 32x32x64, K=512 -> GELU -> Hb (16x16 frag, K2=2048) ----------
// R6-verified: LDS-exchange epilogue.
__global__ __launch_bounds__(256, 4)
void gemm_mx_fc1(const uint8_t* __restrict__ A, const uint8_t* __restrict__ Bw,
                 const float* __restrict__ bias, uint8_t* __restrict__ outb) {
  const int kx = blockIdx.x & 7;
  const int sx = blockIdx.x >> 3;
  const int t = (sx >> 5) * 8 + kx;     // NG = 32
  if (t >= 98) return;
  const int g = sx & 31;
  __shared__ __align__(16) uint8_t Bs[32768];
  const int tid = threadIdx.x;
  const int wave = tid >> 6, lane = tid & 63;
  const long m0 = (long)t * 256;
  const int n0 = g << 6;
  // stage B: 64 cols x 512 K = 32 KB, linear
  const uint8_t* bsrc = Bw + (long)n0 * 512;
  #pragma unroll
  for (int c = 0; c < 8; ++c)
    gload16(bsrc + c * 4096 + tid * 16, Bs + c * 4096 + tid * 16);
  // A: two 32-row panels per wave; MX layout => per slice s, lane reads 32 B at +s*2048+lane*32
  const uint8_t* ab0 = A + (m0 + wave * 64) * 512 + lane * 32;
  const uint8_t* ab1 = ab0 + 16384;
  floatx16 acc[2][2] = {};
  __syncthreads();
  #pragma unroll
  for (int s = 0; s < 8; ++s) {
    const intx8 a0 = cat8(*(const intx4*)(ab0 + s * 2048), *(const intx4*)(ab0 + s * 2048 + 16));
    const intx8 a1 = cat8(*(const intx4*)(ab1 + s * 2048), *(const intx4*)(ab1 + s * 2048 + 16));
    const intx8 b0 = cat8(*(const intx4*)(Bs + s * 2048 + lane * 16),
                          *(const intx4*)(Bs + s * 2048 + 1024 + lane * 16));
    const intx8 b1 = cat8(*(const intx4*)(Bs + 16384 + s * 2048 + lane * 16),
                          *(const intx4*)(Bs + 16384 + s * 2048 + 1024 + lane * 16));
    acc[0][0] = mfma_mx(a0, b0, acc[0][0]);
    acc[0][1] = mfma_mx(a0, b1, acc[0][1]);
    acc[1][0] = mfma_mx(a1, b0, acc[1][0]);
    acc[1][1] = mfma_mx(a1, b1, acc[1][1]);
  }
  // ---- epilogue via LDS exchange (compact 16 KB image -> coalesced dwordx4 stores) ----
  __syncthreads();                 // all waves done reading Bs
  uint8_t* Ex = Bs;
  const int cp = lane & 31;
  const int hl = cp << 1;          // local h pair base 0..62
  const float2 b2 = *(const float2*)(bias + n0 + hl);
  const int hoff = ((hl >> 3) << 4) + (hl & 7);   // o*16 + e
  #pragma unroll
  for (int ri = 0; ri < 2; ++ri)
    #pragma unroll
    for (int q = 0; q < 16; ++q) {
      const int ml = wave * 64 + ri * 32 + 4 * (lane >> 5) + (q & 3) + 8 * (q >> 2);
      const float v0 = fast_gelu(acc[ri][0][q] + b2.x);
      const float v1 = fast_gelu(acc[ri][1][q] + b2.y);
      const int w = pk_fp8<false>(v0, v1, 0);
      const int laddr = ((ml >> 4) << 10) + (((ml & 15) >> 1) << 7) + ((ml & 1) << 3) + hoff;
      *(uint16_t*)(Ex + laddr) = (uint16_t)(w & 0xffff);
    }
  __syncthreads();
  // 1024 16-B units -> Hb: u = p*64 + j2*8 + o
  #pragma unroll
  for (int t2 = 0; t2 < 4; ++t2) {
    const int u = t2 * 256 + tid;
    const long gaddr = (m0 + ((u >> 6) << 4)) * 2048 + (((long)(n0 >> 3) + (u & 7)) << 7)
                     + (((u >> 3) & 7) << 4);
    *(int4*)(outb + gaddr) = *(const int4*)(Ex + u * 16);
  }
}

// ---------- BM table: bias+mask+padding in MFMA C-layout order ----------
__global__ __launch_bounds__(256)
void bm_build(const float* __restrict__ rel_bias, float* __restrict__ BM) {
  const int hw = blockIdx.x;           // head*4 + wpos
  const int head = hw >> 2, wpos = hw & 3;
  const int wi = wpos >> 1, wj = wpos & 1;
  for (int k = 0; k < 4; ++k) {
    const int idx = k * 256 + threadIdx.x;   // tile*64 + lane
    const int tile = idx >> 6, l = idx & 63;
    const int qi = tile >> 2, ti = tile & 3;
    const int n = l & 15, g = l >> 4;
    const int query = qi * 16 + n;
    const int qy = query / 7, qx = query - qy * 7;
    const int hh = wi * 7 + qy, ww = wj * 7 + qx;
    const int ri = (hh < 7 ? 0 : (hh < 11 ? 1 : 2)) * 3 + (ww < 7 ? 0 : (ww < 11 ? 1 : 2));
    float4 ov;
    float vv[4];
    #pragma unroll
    for (int r = 0; r < 4; ++r) {
      const int key = ti * 16 + g * 4 + r;
      float v;
      if (query >= 49 || key >= 49) {
        v = -3.0e38f;
      } else {
        const int ky = key / 7, kx = key - ky * 7;
        const int bidx = (qy - ky + 6) * 13 + (qx - kx + 6);
        const int h2 = wi * 7 + ky, w2 = wj * 7 + kx;
        const int rj = (h2 < 7 ? 0 : (h2 < 11 ? 1 : 2)) * 3 + (w2 < 7 ? 0 : (w2 < 11 ? 1 : 2));
        v = rel_bias[bidx * 16 + head] + ((ri != rj) ? -100.f : 0.f);
      }
      vv[r] = v;
    }
    ov.x = vv[0]; ov.y = vv[1]; ov.z = vv[2]; ov.w = vv[3];
    *(float4*)(BM + ((long)(hw * 16 + tile) << 8) + l * 4) = ov;
  }
}

// ---------- 4x4 byte transpose ----------
__device__ __forceinline__ void tr4(const uint32_t d[4], uint32_t o[4]) {
  #pragma unroll
  for (int c = 0; c < 4; ++c)
    o[c] = ((d[0] >> (8 * c)) & 0xffu) | (((d[1] >> (8 * c)) & 0xffu) << 8)
         | (((d[2] >> (8 * c)) & 0xffu) << 16) | (((d[3] >> (8 * c)) & 0xffu) << 24);
}

// ---------- MFMA windowed attention: one wave per (window, head); AT written frag-major ----------
__global__ __launch_bounds__(256)
void attn_mfma(const uint8_t* __restrict__ QKV, const float* __restrict__ BM,
               uint8_t* __restrict__ AT) {
  __shared__ uint8_t lds[4][9984];   // per-wave: Pb 64x72, Vt 32x72, Ot 64x48
  const int wave = threadIdx.x >> 6, lane = threadIdx.x & 63;
  const int n = lane & 15, g = lane >> 4;
  const int gw = blockIdx.x * 4 + wave;
  const int wd = gw >> 4, head = gw & 15;
  const int b = wd >> 2, wpos = wd & 3;
  const int wi = wpos >> 1, wj = wpos & 1;
  uint8_t* Pb = lds[wave];
  uint8_t* Vt = lds[wave] + 4608;
  uint8_t* Ot = lds[wave] + 6912;
  const long base = (long)b * 196 * 1536;
  auto tok = [&](int slot) -> int {
    const int ty = slot / 7, tx = slot - ty * 7;
    int h = wi * 7 + ty + 3; if (h >= 14) h -= 14;
    int w = wj * 7 + tx + 3; if (w >= 14) w -= 14;
    return h * 14 + w;
  };
  long Ak[4], Bq[4];
  #pragma unroll
  for (int t4 = 0; t4 < 4; ++t4) {
    int slot = t4 * 16 + n; if (slot > 48) slot = 48;
    const long tb = base + (long)tok(slot) * 1536 + head * 32 + g * 8;
    Bq[t4] = *(const long*)(QKV + tb);          // Q rows (B operand)
    Ak[t4] = *(const long*)(QKV + tb + 512);    // K rows (A operand)
  }
  #pragma unroll
  for (int bb2 = 0; bb2 < 2; ++bb2) {
    const int blk = lane + bb2 * 64;
    const int dq = blk >> 4, tq = blk & 15;
    uint32_t d4[4], o4[4];
    #pragma unroll
    for (int r = 0; r < 4; ++r) {
      int slot = tq * 4 + r; if (slot > 48) slot = 48;
      d4[r] = *(const uint32_t*)(QKV + base + (long)tok(slot) * 1536 + 1024 + head * 32 + dq * 4);
    }
    tr4(d4, o4);
    #pragma unroll
    for (int c = 0; c < 4; ++c)
      *(uint32_t*)(Vt + (dq * 4 + c) * 72 + tq * 4) = o4[c];
  }
  floatx4 acc[4][4];
  const float* bmw = BM + ((long)(head * 4 + wpos) << 12) + lane * 4;
  #pragma unroll
  for (int qi = 0; qi < 4; ++qi)
    #pragma unroll
    for (int ti = 0; ti < 4; ++ti) {
      const float4 bv = *(const float4*)(bmw + ((qi * 4 + ti) << 8));
      acc[qi][ti][0] = bv.x; acc[qi][ti][1] = bv.y;
      acc[qi][ti][2] = bv.z; acc[qi][ti][3] = bv.w;
    }
  #pragma unroll
  for (int qi = 0; qi < 4; ++qi)
    #pragma unroll
    for (int ti = 0; ti < 4; ++ti)
      acc[qi][ti] = __builtin_amdgcn_mfma_f32_16x16x32_fp8_fp8(Ak[ti], Bq[qi], acc[qi][ti], 0, 0, 0);
  #pragma unroll
  for (int qi = 0; qi < 4; ++qi) {
    float mx = -3.0e38f;
    #pragma unroll
    for (int ti = 0; ti < 4; ++ti)
      #pragma unroll
      for (int r = 0; r < 4; ++r) mx = fmaxf(mx, acc[qi][ti][r]);
    mx = fmaxf(mx, __shfl_xor(mx, 16));
    mx = fmaxf(mx, __shfl_xor(mx, 32));
    float sum = 0.f;
    #pragma unroll
    for (int ti = 0; ti < 4; ++ti)
      #pragma unroll
      for (int r = 0; r < 4; ++r) {
        const float e = __expf(acc[qi][ti][r] - mx);
        acc[qi][ti][r] = e; sum += e;
      }
    sum += __shfl_xor(sum, 16);
    sum += __shfl_xor(sum, 32);
    const float inv = 1.f / sum;
    #pragma unroll
    for (int ti = 0; ti < 4; ++ti) {
      const int pw = pk_fp8x4(acc[qi][ti][0] * inv, acc[qi][ti][1] * inv,
                              acc[qi][ti][2] * inv, acc[qi][ti][3] * inv);
      *(uint32_t*)(Pb + (qi * 16 + n) * 72 + ti * 16 + g * 4) = pw;
    }
  }
  asm volatile("s_waitcnt lgkmcnt(0)" ::: "memory");
  long Bv[2][2];
  #pragma unroll
  for (int ni = 0; ni < 2; ++ni)
    #pragma unroll
    for (int s = 0; s < 2; ++s)
      Bv[ni][s] = *(const long*)(Vt + (ni * 16 + n) * 72 + s * 32 + g * 8);
  floatx4 o[4][2] = {};
  #pragma unroll
  for (int qi = 0; qi < 4; ++qi)
    #pragma unroll
    for (int s = 0; s < 2; ++s) {
      const long Ap = *(const long*)(Pb + (qi * 16 + n) * 72 + s * 32 + g * 8);
      #pragma unroll
      for (int ni = 0; ni < 2; ++ni)
        o[qi][ni] = __builtin_amdgcn_mfma_f32_16x16x32_fp8_fp8(Ap, Bv[ni][s], o[qi][ni], 0, 0, 0);
    }
  #pragma unroll
  for (int qi = 0; qi < 4; ++qi)
    #pragma unroll
    for (int ni = 0; ni < 2; ++ni)
      #pragma unroll
      for (int r = 0; r < 4; ++r)
        Ot[(qi * 16 + g * 4 + r) * 48 + ni * 16 + n] =
            (uint8_t)(pk_fp8<false>(o[qi][ni][r], 0.f, 0) & 0xff);
  asm volatile("s_waitcnt lgkmcnt(0)" ::: "memory");
  if (lane < 49) {
    const int m = b * 196 + tok(lane);
    uint8_t* opb = AT + (long)(m & ~15) * 512 + ((m & 15) << 3);
    #pragma unroll
    for (int d8 = 0; d8 < 4; ++d8)
      *(long*)(opb + (head * 4 + d8) * 128) = *(const long*)(Ot + lane * 48 + d8 * 8);
  }
}

extern "C" void kernel_launch(void* const* d_in, const int* in_sizes, int n_in,
                              void* d_out, int out_size, void* d_ws, size_t ws_size,
                              hipStream_t stream) {
  const float* x      = (const float*)d_in[0];
  const float* ln1_w  = (const float*)d_in[1];
  const float* ln1_b  = (const float*)d_in[2];
  const float* qkv_w  = (const float*)d_in[3];
  const float* qkv_b  = (const float*)d_in[4];
  const float* relb   = (const float*)d_in[5];
  const float* proj_w = (const float*)d_in[6];
  const float* proj_b = (const float*)d_in[7];
  const float* gamma1 = (const float*)d_in[8];
  const float* ln2_w  = (const float*)d_in[9];
  const float* ln2_b  = (const float*)d_in[10];
  const float* fc1_w  = (const float*)d_in[11];
  const float* fc1_b  = (const float*)d_in[12];
  const float* fc2_w  = (const float*)d_in[13];
  const float* fc2_b  = (const float*)d_in[14];
  const float* gamma2 = (const float*)d_in[15];
  float* out = (float*)d_out;
  char* ws = (char*)d_ws;

  float*    mu1 = (float*)(ws + 0);
  float*    rs1 = (float*)(ws + 100352);
  float*    S1  = (float*)(ws + 200704);      // LN2 raw sum
  float*    S2  = (float*)(ws + 301056);      // LN2 raw sumsq
  uint8_t*  Wq  = (uint8_t*)(ws + 401408);    //   786,432 B (MX-B layout)
  uint8_t*  Wp  = (uint8_t*)(ws + 1187840);   //   262,144 B frag-major
  uint8_t*  W1  = (uint8_t*)(ws + 1449984);   // 1,048,576 B (MX-B layout)
  uint8_t*  W2  = (uint8_t*)(ws + 2498560);   // 1,048,576 B frag-major
  float*    BMt = (float*)  (ws + 3547136);   // 1,048,576 B bias+mask table
  uint8_t*  Afp = (uint8_t*)(ws + 4595712);   // 12,845,056 B tokens (MX-A: LN1, later LN2)
  uint16_t* X1b = (uint16_t*)(ws + 68820992); // 25,690,112 B token-major bf16
  uint8_t*  QKV = (uint8_t*)(ws + 120201216); // 38,535,168 B token-major fp8
  uint8_t*  AT  = (uint8_t*)(ws + 158736384); // 12,845,056 B frag-major fp8
  uint8_t*  Hb  = (uint8_t*)(ws + 120201216); // 51,380,224 B 16x16 frag-major, overlaps dead QKV+AT

  // zero LN2 sum buffers (atomics accumulate during proj epilogue)
  hipMemsetAsync(ws + 200704, 0, 200704, stream);

  // weights -> fp8 (MX-B for qkv/fc1; 16x16 frag for proj/fc2), BM table
  cvt_frag_mx512<<<768,  256, 0, stream>>>(qkv_w, Wq, 196608);
  cvt_frag<512> <<<256,  256, 0, stream>>>(proj_w, Wp, 65536);
  cvt_frag_mx512<<<1024, 256, 0, stream>>>(fc1_w, W1, 262144);
  cvt_frag<2048><<<1024, 256, 0, stream>>>(fc2_w, W2, 262144);
  bm_build<<<64, 256, 0, stream>>>(relb, BMt);

  // LN1 -> MX-A fp8 tokens
  ln_stats_nchw<<<392, 256, 0, stream>>>(x, mu1, rs1);
  ln1_apply<<<4096, 256, 0, stream>>>(x, mu1, rs1, ln1_w, ln1_b, Afp);

  // qkv: MX 32x32x64 GEMM (q pre-scaled) -> token-major QKV: grid 8*13*24 = 2496
  gemm_mx_qkv<<<2496, 256, 0, stream>>>(Afp, Wq, qkv_b, QKV);

  // shifted-window attention (MFMA), frag-major AT out
  attn_mfma<<<2048, 256, 0, stream>>>(QKV, BMt, AT);

  // proj GEMM: X1b(bf16) = x(NCHW) + g1*(out+b); fused LN2 stats: T=98, NG=8 -> 832
  gemm_bl<4, 512, 1, 8, 98><<<832, 256, 0, stream>>>(AT, Wp, proj_b, x, nullptr, gamma1, nullptr, nullptr, X1b, S1, S2, 512);

  // LN2 apply -> MX-A fp8 tokens
  ln2_panel<<<1568, 256, 0, stream>>>(X1b, S1, S2, ln2_w, ln2_b, Afp);

  // fc1: MX-scaled 32x32x64 GEMM + GELU -> Hb (16x16 frag): grid 8*13*32 = 3328
  gemm_mx_fc1<<<3328, 256, 0, stream>>>(Afp, W1, fc1_b, Hb);

  // fc2 (T=196, NG=8 -> 1600) -> NCHW out via LDS exchange
  gemm_bl<2, 2048, 3, 8, 196><<<1600, 256, 0, stream>>>(Hb, W2, fc2_b, nullptr, X1b, gamma2, nullptr, out, nullptr, nullptr, nullptr, 512);
}

// Round 13
// 349.323 us; speedup vs baseline: 1.0597x; 1.0382x over previous
//
#include <hip/hip_runtime.h>
#include <cmath>
#include <cstdint>

typedef float floatx4 __attribute__((ext_vector_type(4)));
typedef float floatx16 __attribute__((ext_vector_type(16)));
typedef int   intx4   __attribute__((ext_vector_type(4)));
typedef int   intx8   __attribute__((ext_vector_type(8)));

#define EPS_ 1e-5f
#define QSCALE 0.17677669529663689f

// ---------- async global->LDS (16B per lane) ----------
__device__ __forceinline__ void gload16(const uint8_t* g, uint8_t* l) {
  __builtin_amdgcn_global_load_lds(
      (const __attribute__((address_space(1))) void*)g,
      (__attribute__((address_space(3))) void*)l, 16, 0, 0);
}

// ---------- fp8 e4m3 pack (word-select must be an immediate) ----------
template<bool HI>
__device__ __forceinline__ int pk_fp8(float a, float b, int old) {
  return __builtin_amdgcn_cvt_pk_fp8_f32(a, b, old, HI);
}
__device__ __forceinline__ int pk_fp8x4(float v0, float v1, float v2, float v3) {
  int w = pk_fp8<false>(v0, v1, 0);
  return pk_fp8<true>(v2, v3, w);
}

// ---------- bf16 helpers (RNE) ----------
__device__ __forceinline__ uint16_t f2bf(float f) {
  uint32_t u = __float_as_uint(f);
  return (uint16_t)((u + 0x7fffu + ((u >> 16) & 1u)) >> 16);
}
__device__ __forceinline__ float bf2f(uint16_t h) {
  return __uint_as_float(((uint32_t)h) << 16);
}

// ---------- fast GELU: x*sigmoid(1.702x) (error << fp8 quant; branch scaled by 1e-6) ----------
__device__ __forceinline__ float fast_gelu(float v) {
  const float t = __expf(-1.702f * v);
  return v * __builtin_amdgcn_rcpf(1.f + t);
}

// ---------- MX-scaled fp8 MFMA (unity scales: E8M0 127 = 2^0) ----------
__device__ __forceinline__ intx8 cat8(intx4 a, intx4 b) {
  return __builtin_shufflevector(a, b, 0, 1, 2, 3, 4, 5, 6, 7);
}
__device__ __forceinline__ floatx16 mfma_mx(intx8 a, intx8 b, floatx16 c) {
  return __builtin_amdgcn_mfma_scale_f32_32x32x64_f8f6f4(
      a, b, c, 0, 0, 0, 0x7F7F7F7F, 0, 0x7F7F7F7F);
}

// 16x16 fragment-major layout (proj/fc2 operands):
//   addr(m, k) = (m & ~15)*K + (k>>3)*128 + (m & 15)*8 + (k & 7)
// MX 32x32 A layout (qkv/fc1 A tokens): addr(m,k) = (m>>5)*32*K + (k>>5)*1024 + (m&31)*32 + (k&31)
// MX 32x32 B layout (Wq/W1, col-pair permuted): lane holds cols n0+2*(lane&31)+{0,1}

// ---------- fp32 weights -> fp8 frag-major 16x16 (col-permuted) ----------
template<int K>
__global__ void cvt_frag(const float* __restrict__ s, uint8_t* __restrict__ d, int n4) {
  const int i = blockIdx.x * 256 + threadIdx.x;
  if (i >= n4) return;
  const int kq = K >> 2;
  const int n = i / kq;
  const int k = (i - n * kq) << 2;
  const float4 v = ((const float4*)s)[i];
  const int panel = ((n >> 6) << 2) + (n & 3);
  const int lm = (n >> 2) & 15;
  const long addr = (long)panel * (16 * K) + ((k >> 3) << 7) + (lm << 3) + (k & 4);
  *(int*)(d + addr) = pk_fp8x4(v.x, v.y, v.z, v.w);
}

// ---------- fp32 weights -> fp8 MX 32x32 B layout (K=512; any N multiple of 64) ----------
__global__ void cvt_frag_mx512(const float* __restrict__ s, uint8_t* __restrict__ d, int n4) {
  const int i = blockIdx.x * 256 + threadIdx.x;
  if (i >= n4) return;
  const int n = i >> 7;               // out-channel (col), K/4 = 128
  const int k = (i & 127) << 2;
  const float4 v = ((const float4*)s)[i];
  const long addr = (long)(n >> 6) * 32768 + (n & 1) * 16384 + ((k >> 6) << 11)
                  + (((k >> 4) & 1) << 10)
                  + ((((k >> 5) & 1) << 5) + ((n & 63) >> 1)) * 16 + (k & 15);
  *(int*)(d + addr) = pk_fp8x4(v.x, v.y, v.z, v.w);
}

// ---------- LN1 stats over C for NCHW input ----------
__global__ __launch_bounds__(256)
void ln_stats_nchw(const float* __restrict__ x, float* __restrict__ mu, float* __restrict__ rs) {
  const int tl = threadIdx.x & 63;
  const int wv = threadIdx.x >> 6;
  const int t = blockIdx.x * 64 + tl;       // token = b*196 + p
  const int b = t / 196;
  const int p = t - b * 196;
  const float* xp = x + (long)b * 100352 + p;
  float s = 0.f, ss = 0.f;
  const int cbeg = wv * 128;
  for (int c = cbeg; c < cbeg + 128; ++c) {
    const float v = xp[(long)c * 196];
    s += v; ss += v * v;
  }
  __shared__ float sb[4][64], qb[4][64];
  sb[wv][tl] = s; qb[wv][tl] = ss;
  __syncthreads();
  if (wv == 0) {
    s  = sb[0][tl] + sb[1][tl] + sb[2][tl] + sb[3][tl];
    ss = qb[0][tl] + qb[1][tl] + qb[2][tl] + qb[3][tl];
    const float m = s * (1.f / 512.f);
    const float var = ss * (1.f / 512.f) - m * m;
    mu[t] = m;
    rs[t] = rsqrtf(var + EPS_);
  }
}

// ---------- LN1 apply: NCHW -> MX-A fp8 tokens + token-major f32 x copy (Xt) ----------
// R13: also emits Xt[t*512+c] (coalesced float4) so proj's residual read is coalesced
// instead of 64 scattered stride-196 dword loads (R12 counters: proj MfmaUtil 8.8%,
// occupancy 19% — pure latency stall on the NCHW gather).
__global__ __launch_bounds__(256)
void ln1_apply(const float* __restrict__ x, const float* __restrict__ mu, const float* __restrict__ rs,
               const float* __restrict__ w, const float* __restrict__ bb,
               uint8_t* __restrict__ A, float* __restrict__ xt) {
  __shared__ float tile[64][53];
  const int bid = blockIdx.x;
  const int ct = bid & 7;
  const int pt = (bid >> 3) & 3;
  const int b = bid >> 5;
  const int p0 = pt * 49, c0 = ct * 64;
  const long xbase = (long)b * 100352;
  for (int idx = threadIdx.x; idx < 3136; idx += 256) {
    const int cl = idx / 49;
    const int pl = idx - cl * 49;
    tile[cl][pl] = x[xbase + (long)(c0 + cl) * 196 + p0 + pl];
  }
  __syncthreads();
  const int tbase = b * 196 + p0;
  for (int idx = threadIdx.x; idx < 784; idx += 256) {
    const int pl = idx >> 4;                // 0..48
    const int cq = (idx & 15) << 2;         // 0..60 step 4
    const int t = tbase + pl;
    const int c = c0 + cq;
    const float m = mu[t], rr = rs[t];
    const float r0 = tile[cq + 0][pl];
    const float r1 = tile[cq + 1][pl];
    const float r2 = tile[cq + 2][pl];
    const float r3 = tile[cq + 3][pl];
    // token-major f32 copy for proj's residual (coalesced 16 B/lane)
    *(float4*)(xt + (long)t * 512 + c) = make_float4(r0, r1, r2, r3);
    const float v0 = (r0 - m) * rr * w[c + 0] + bb[c + 0];
    const float v1 = (r1 - m) * rr * w[c + 1] + bb[c + 1];
    const float v2 = (r2 - m) * rr * w[c + 2] + bb[c + 2];
    const float v3 = (r3 - m) * rr * w[c + 3] + bb[c + 3];
    // MX A layout: (t>>5)*16384 + (c>>5)*1024 + (t&31)*32 + (c&31)
    const long addr = (long)(t >> 5) * 16384 + ((c >> 5) << 10) + ((t & 31) << 5) + (c & 31);
    *(int*)(A + addr) = pk_fp8x4(v0, v1, v2, v3);
  }
}

// ---------- LN2: one block per 16-token panel; X1 bf16 -> MX 32x32 A-layout fp8 ----------
__global__ __launch_bounds__(256)
void ln2_panel(const uint16_t* __restrict__ Xb, const float* __restrict__ S1,
               const float* __restrict__ S2, const float* __restrict__ w,
               const float* __restrict__ bb, uint8_t* __restrict__ Z) {
  __shared__ float xs[16 * 516];
  const int p = blockIdx.x;
  const int t0 = p * 16;
  for (int idx = threadIdx.x; idx < 1024; idx += 256) {
    const int tl = idx >> 6;                 // token 0..15
    const int c8 = (idx & 63) << 3;          // 0..504 step 8
    const uint4 raw = *(const uint4*)(Xb + ((long)(t0 + tl) << 9) + c8);
    float* xr = xs + tl * 516 + c8;
    xr[0] = bf2f((uint16_t)(raw.x & 0xffff)); xr[1] = bf2f((uint16_t)(raw.x >> 16));
    xr[2] = bf2f((uint16_t)(raw.y & 0xffff)); xr[3] = bf2f((uint16_t)(raw.y >> 16));
    xr[4] = bf2f((uint16_t)(raw.z & 0xffff)); xr[5] = bf2f((uint16_t)(raw.z >> 16));
    xr[6] = bf2f((uint16_t)(raw.w & 0xffff)); xr[7] = bf2f((uint16_t)(raw.w >> 16));
  }
  __syncthreads();
  for (int e = threadIdx.x; e < 2048; e += 256) {
    const int tl = e >> 7;             // token 0..15
    const int c  = (e & 127) << 2;     // channel 0..508 step 4
    const int t = t0 + tl;
    const float m = S1[t] * (1.f / 512.f);
    const float var = S2[t] * (1.f / 512.f) - m * m;
    const float r = rsqrtf(var + EPS_);
    const float* xr = xs + tl * 516 + c;
    const float v0 = (xr[0] - m) * r * w[c + 0] + bb[c + 0];
    const float v1 = (xr[1] - m) * r * w[c + 1] + bb[c + 1];
    const float v2 = (xr[2] - m) * r * w[c + 2] + bb[c + 2];
    const float v3 = (xr[3] - m) * r * w[c + 3] + bb[c + 3];
    // MX A layout: (t>>5)*16384 + (c>>5)*1024 + (t&31)*32 + (c&31)
    const long addr = (long)(t >> 5) * 16384 + ((c >> 5) << 10) + ((t & 31) << 5) + (c & 31);
    *(int*)(Z + addr) = pk_fp8x4(v0, v1, v2, v3);
  }
}

// ---------- fp8 16x16 MFMA GEMM (R1-verified structure): B LDS, A direct-global ----------
// 4 waves x (MI*16 rows) x 64 cols; A prefetch dist 2; XCD-swizzled grid.
// EPI 1: proj -> bf16 X1 = xt(token-major f32) + g1*(acc+b); fused LN2 raw-sum atomics
// EPI 3: fc2 -> f32 NCHW via LDS exchange (MI=2: 128 rows)
template<int MI, int K, int EPI, int NG, int T>
__global__ __launch_bounds__(256, 4)
void gemm_bl(const uint8_t* __restrict__ A, const uint8_t* __restrict__ Bw,
             const float* __restrict__ bias, const float* __restrict__ res,
             const uint16_t* __restrict__ resb, const float* __restrict__ gamma,
             uint8_t* __restrict__ outb, float* __restrict__ outf,
             uint16_t* __restrict__ outh, float* __restrict__ S1, float* __restrict__ S2,
             const int N) {
  const int kx = blockIdx.x & 7;
  const int sx = blockIdx.x >> 3;
  const int t = (sx / NG) * 8 + kx;
  if (t >= T) return;
  const int g = sx - (sx / NG) * NG;        // 64-col group
  __shared__ __align__(16) uint8_t Bs[(EPI == 3) ? 33280 : 32768];
  const int tid = threadIdx.x;
  const int wave = tid >> 6, lane = tid & 63;
  const int lm = lane & 15, lq = lane >> 4;
  const long m0 = (long)t * (MI * 64);
  const long n0 = (long)g << 6;
  const uint8_t* abase = A + (m0 + wave * MI * 16) * (long)K + (lane << 3);
  floatx4 acc[MI][4] = {};
  constexpr int NKS = K / 32;
  long aP0[MI], aP1[MI];
  #pragma unroll
  for (int i = 0; i < MI; ++i) {
    aP0[i] = *(const long*)(abase + (long)i * 16 * K);
    aP1[i] = *(const long*)(abase + (long)i * 16 * K + 512);
  }
  #pragma unroll
  for (int ph = 0; ph < K / 512; ++ph) {
    const uint8_t* bsrc = Bw + n0 * K + ph * 8192;
    #pragma unroll
    for (int j = 0; j < 4; ++j)
      #pragma unroll
      for (int c = 0; c < 2; ++c)
        gload16(bsrc + (long)j * 16 * K + c * 4096 + tid * 16,
                Bs + j * 8192 + c * 4096 + tid * 16);
    __syncthreads();
    #pragma unroll
    for (int ksl = 0; ksl < 16; ++ksl) {
      const int sg = ph * 16 + ksl;
      long aC[MI];
      #pragma unroll
      for (int i = 0; i < MI; ++i) aC[i] = (ksl & 1) ? aP1[i] : aP0[i];
      if (sg + 2 < NKS) {
        #pragma unroll
        for (int i = 0; i < MI; ++i) {
          const long v = *(const long*)(abase + (long)i * 16 * K + (long)(sg + 2) * 512);
          if (ksl & 1) aP1[i] = v; else aP0[i] = v;
        }
      }
      long bf[4];
      #pragma unroll
      for (int j = 0; j < 4; ++j)
        bf[j] = *(const long*)(Bs + j * 8192 + ksl * 512 + (lane << 3));
      __builtin_amdgcn_s_setprio(1);
      #pragma unroll
      for (int i = 0; i < MI; ++i)
        #pragma unroll
        for (int j = 0; j < 4; ++j)
          acc[i][j] = __builtin_amdgcn_mfma_f32_16x16x32_fp8_fp8(aC[i], bf[j], acc[i][j], 0, 0, 0);
      __builtin_amdgcn_s_setprio(0);
    }
    if (K / 512 > 1 && ph + 1 < K / 512) __syncthreads();
  }
  const int cb = (g << 6) + (lm << 2);
  const float4 b4 = *(const float4*)(bias + cb);
  float4 g4 = make_float4(0.f, 0.f, 0.f, 0.f);
  if (EPI == 1 || EPI == 3) g4 = *(const float4*)(gamma + cb);
  if (EPI != 3) {
    #pragma unroll
    for (int i = 0; i < MI; ++i) {
      #pragma unroll
      for (int r = 0; r < 4; ++r) {
        const long rowg = m0 + wave * MI * 16 + i * 16 + lq * 4 + r;
        float v0 = acc[i][0][r] + b4.x;
        float v1 = acc[i][1][r] + b4.y;
        float v2 = acc[i][2][r] + b4.z;
        float v3 = acc[i][3][r] + b4.w;
        {   // EPI 1: residual from token-major f32 Xt (coalesced 16 B/lane)
          const float4 xr4 = *(const float4*)(res + rowg * 512 + cb);
          const float o0 = xr4.x + g4.x * v0;
          const float o1 = xr4.y + g4.y * v1;
          const float o2 = xr4.z + g4.z * v2;
          const float o3 = xr4.w + g4.w * v3;
          ushort4 hv;
          hv.x = f2bf(o0); hv.y = f2bf(o1); hv.z = f2bf(o2); hv.w = f2bf(o3);
          *(ushort4*)(outh + rowg * 512 + cb) = hv;
          const float q0 = bf2f(hv.x), q1 = bf2f(hv.y), q2 = bf2f(hv.z), q3 = bf2f(hv.w);
          float s = q0 + q1 + q2 + q3;
          float ss = q0 * q0 + q1 * q1 + q2 * q2 + q3 * q3;
          s += __shfl_xor(s, 1);  ss += __shfl_xor(ss, 1);
          s += __shfl_xor(s, 2);  ss += __shfl_xor(ss, 2);
          s += __shfl_xor(s, 4);  ss += __shfl_xor(ss, 4);
          s += __shfl_xor(s, 8);  ss += __shfl_xor(ss, 8);
          if (lm == 0) {
            atomicAdd(S1 + rowg, s);
            atomicAdd(S2 + rowg, ss);
          }
        }
      }
    }
  } else {
    // EPI 3 (MI=2): 128-row tile -> NCHW via LDS exchange, coalesced (stride 129)
    float* Tx = (float*)Bs;
    __syncthreads();
    #pragma unroll
    for (int i = 0; i < MI; ++i) {
      #pragma unroll
      for (int r = 0; r < 4; ++r) {
        const long rowg = m0 + wave * MI * 16 + i * 16 + lq * 4 + r;
        const int rl = (int)(rowg - m0);   // 0..127
        const ushort4 rb = *(const ushort4*)(resb + rowg * 512 + cb);
        Tx[(lm * 4 + 0) * 129 + rl] = bf2f(rb.x) + g4.x * (acc[i][0][r] + b4.x);
        Tx[(lm * 4 + 1) * 129 + rl] = bf2f(rb.y) + g4.y * (acc[i][1][r] + b4.y);
        Tx[(lm * 4 + 2) * 129 + rl] = bf2f(rb.z) + g4.z * (acc[i][2][r] + b4.z);
        Tx[(lm * 4 + 3) * 129 + rl] = bf2f(rb.w) + g4.w * (acc[i][3][r] + b4.w);
      }
    }
    __syncthreads();
    #pragma unroll
    for (int t2 = 0; t2 < 32; ++t2) {
      const int idx = t2 * 256 + tid;
      const int rl = idx & 127;
      const int ch = idx >> 7;
      const unsigned m = (unsigned)(m0 + rl);
      const unsigned bi = m / 196u;
      const unsigned p = m - bi * 196u;
      outf[(long)bi * 100352 + (long)(n0 + ch) * 196 + p] = Tx[ch * 129 + rl];
    }
  }
}

// ---------- qkv: MX-scaled fp8 GEMM, 32x32x64, K=512 -> fp8 token-major QKV ----------
// R10-verified: token-contiguous 16 KB LDS image -> coalesced token-major stores.
__global__ __launch_bounds__(256, 4)
void gemm_mx_qkv(const uint8_t* __restrict__ A, const uint8_t* __restrict__ Bw,
                 const float* __restrict__ bias, uint8_t* __restrict__ outb) {
  const int kx = blockIdx.x & 7;
  const int sx = blockIdx.x >> 3;
  const int t = (sx / 24) * 8 + kx;     // NG = 24
  if (t >= 98) return;
  const int g = sx - (sx / 24) * 24;
  __shared__ __align__(16) uint8_t Bs[32768];
  const int tid = threadIdx.x;
  const int wave = tid >> 6, lane = tid & 63;
  const long m0 = (long)t * 256;
  const int n0 = g << 6;
  // stage B: 64 cols x 512 K = 32 KB, linear (MX-B layout block)
  const uint8_t* bsrc = Bw + (long)n0 * 512;
  #pragma unroll
  for (int c = 0; c < 8; ++c)
    gload16(bsrc + c * 4096 + tid * 16, Bs + c * 4096 + tid * 16);
  // A: two 32-row panels per wave; MX-A layout
  const uint8_t* ab0 = A + (m0 + wave * 64) * 512 + lane * 32;
  const uint8_t* ab1 = ab0 + 16384;
  floatx16 acc[2][2] = {};
  __syncthreads();
  #pragma unroll
  for (int s = 0; s < 8; ++s) {
    const intx8 a0 = cat8(*(const intx4*)(ab0 + s * 2048), *(const intx4*)(ab0 + s * 2048 + 16));
    const intx8 a1 = cat8(*(const intx4*)(ab1 + s * 2048), *(const intx4*)(ab1 + s * 2048 + 16));
    const intx8 b0 = cat8(*(const intx4*)(Bs + s * 2048 + lane * 16),
                          *(const intx4*)(Bs + s * 2048 + 1024 + lane * 16));
    const intx8 b1 = cat8(*(const intx4*)(Bs + 16384 + s * 2048 + lane * 16),
                          *(const intx4*)(Bs + 16384 + s * 2048 + 1024 + lane * 16));
    acc[0][0] = mfma_mx(a0, b0, acc[0][0]);
    acc[0][1] = mfma_mx(a0, b1, acc[0][1]);
    acc[1][0] = mfma_mx(a1, b0, acc[1][0]);
    acc[1][1] = mfma_mx(a1, b1, acc[1][1]);
  }
  // ---- epilogue: 16 KB token-contiguous LDS image -> coalesced token-major stores ----
  __syncthreads();                 // all waves done reading Bs
  uint8_t* Ex = Bs;
  const int cp = lane & 31;
  const int hl = cp << 1;          // local col pair base 0..62 (even)
  const float2 b2 = *(const float2*)(bias + n0 + hl);
  const float qs = (n0 + hl < 512) ? QSCALE : 1.f;   // pair-uniform (hl even, 512 even)
  #pragma unroll
  for (int ri = 0; ri < 2; ++ri)
    #pragma unroll
    for (int q = 0; q < 16; ++q) {
      const int ml = wave * 64 + ri * 32 + 4 * (lane >> 5) + (q & 3) + 8 * (q >> 2);
      const float v0 = (acc[ri][0][q] + b2.x) * qs;
      const float v1 = (acc[ri][1][q] + b2.y) * qs;
      const int w = pk_fp8<false>(v0, v1, 0);
      *(uint16_t*)(Ex + ml * 64 + hl) = (uint16_t)(w & 0xffff);
    }
  __syncthreads();
  // 1024 16-B units -> QKV token-major: row = u>>2, chunk = u&3
  #pragma unroll
  for (int t2 = 0; t2 < 4; ++t2) {
    const int u = t2 * 256 + tid;
    const long gaddr = (m0 + (u >> 2)) * 1536 + n0 + ((u & 3) << 4);
    *(int4*)(outb + gaddr) = *(const int4*)(Ex + u * 16);
  }
}

// ---------- fc1: MX-scaled fp8 GEMM, 32x32x64, K=512 -> GELU -> Hb (16x16 frag, K2=2048) ----------
// R6-verified: LDS-exchange epilogue.
__global__ __launch_bounds__(256, 4)
void gemm_mx_fc1(const uint8_t* __restrict__ A, const uint8_t* __restrict__ Bw,
                 const float* __restrict__ bias, uint8_t* __restrict__ outb) {
  const int kx = blockIdx.x & 7;
  const int sx = blockIdx.x >> 3;
  const int t = (sx >> 5) * 8 + kx;     // NG = 32
  if (t >= 98) return;
  const int g = sx & 31;
  __shared__ __align__(16) uint8_t Bs[32768];
  const int tid = threadIdx.x;
  const int wave = tid >> 6, lane = tid & 63;
  const long m0 = (long)t * 256;
  const int n0 = g << 6;
  // stage B: 64 cols x 512 K = 32 KB, linear
  const uint8_t* bsrc = Bw + (long)n0 * 512;
  #pragma unroll
  for (int c = 0; c < 8; ++c)
    gload16(bsrc + c * 4096 + tid * 16, Bs + c * 4096 + tid * 16);
  // A: two 32-row panels per wave; MX layout => per slice s, lane reads 32 B at +s*2048+lane*32
  const uint8_t* ab0 = A + (m0 + wave * 64) * 512 + lane * 32;
  const uint8_t* ab1 = ab0 + 16384;
  floatx16 acc[2][2] = {};
  __syncthreads();
  #pragma unroll
  for (int s = 0; s < 8; ++s) {
    const intx8 a0 = cat8(*(const intx4*)(ab0 + s * 2048), *(const intx4*)(ab0 + s * 2048 + 16));
    const intx8 a1 = cat8(*(const intx4*)(ab1 + s * 2048), *(const intx4*)(ab1 + s * 2048 + 16));
    const intx8 b0 = cat8(*(const intx4*)(Bs + s * 2048 + lane * 16),
                          *(const intx4*)(Bs + s * 2048 + 1024 + lane * 16));
    const intx8 b1 = cat8(*(const intx4*)(Bs + 16384 + s * 2048 + lane * 16),
                          *(const intx4*)(Bs + 16384 + s * 2048 + 1024 + lane * 16));
    acc[0][0] = mfma_mx(a0, b0, acc[0][0]);
    acc[0][1] = mfma_mx(a0, b1, acc[0][1]);
    acc[1][0] = mfma_mx(a1, b0, acc[1][0]);
    acc[1][1] = mfma_mx(a1, b1, acc[1][1]);
  }
  // ---- epilogue via LDS exchange (compact 16 KB image -> coalesced dwordx4 stores) ----
  __syncthreads();                 // all waves done reading Bs
  uint8_t* Ex = Bs;
  const int cp = lane & 31;
  const int hl = cp << 1;          // local h pair base 0..62
  const float2 b2 = *(const float2*)(bias + n0 + hl);
  const int hoff = ((hl >> 3) << 4) + (hl & 7);   // o*16 + e
  #pragma unroll
  for (int ri = 0; ri < 2; ++ri)
    #pragma unroll
    for (int q = 0; q < 16; ++q) {
      const int ml = wave * 64 + ri * 32 + 4 * (lane >> 5) + (q & 3) + 8 * (q >> 2);
      const float v0 = fast_gelu(acc[ri][0][q] + b2.x);
      const float v1 = fast_gelu(acc[ri][1][q] + b2.y);
      const int w = pk_fp8<false>(v0, v1, 0);
      const int laddr = ((ml >> 4) << 10) + (((ml & 15) >> 1) << 7) + ((ml & 1) << 3) + hoff;
      *(uint16_t*)(Ex + laddr) = (uint16_t)(w & 0xffff);
    }
  __syncthreads();
  // 1024 16-B units -> Hb: u = p*64 + j2*8 + o
  #pragma unroll
  for (int t2 = 0; t2 < 4; ++t2) {
    const int u = t2 * 256 + tid;
    const long gaddr = (m0 + ((u >> 6) << 4)) * 2048 + (((long)(n0 >> 3) + (u & 7)) << 7)
                     + (((u >> 3) & 7) << 4);
    *(int4*)(outb + gaddr) = *(const int4*)(Ex + u * 16);
  }
}

// ---------- BM table: bias+mask+padding in MFMA C-layout order ----------
__global__ __launch_bounds__(256)
void bm_build(const float* __restrict__ rel_bias, float* __restrict__ BM) {
  const int hw = blockIdx.x;           // head*4 + wpos
  const int head = hw >> 2, wpos = hw & 3;
  const int wi = wpos >> 1, wj = wpos & 1;
  for (int k = 0; k < 4; ++k) {
    const int idx = k * 256 + threadIdx.x;   // tile*64 + lane
    const int tile = idx >> 6, l = idx & 63;
    const int qi = tile >> 2, ti = tile & 3;
    const int n = l & 15, g = l >> 4;
    const int query = qi * 16 + n;
    const int qy = query / 7, qx = query - qy * 7;
    const int hh = wi * 7 + qy, ww = wj * 7 + qx;
    const int ri = (hh < 7 ? 0 : (hh < 11 ? 1 : 2)) * 3 + (ww < 7 ? 0 : (ww < 11 ? 1 : 2));
    float4 ov;
    float vv[4];
    #pragma unroll
    for (int r = 0; r < 4; ++r) {
      const int key = ti * 16 + g * 4 + r;
      float v;
      if (query >= 49 || key >= 49) {
        v = -3.0e38f;
      } else {
        const int ky = key / 7, kx = key - ky * 7;
        const int bidx = (qy - ky + 6) * 13 + (qx - kx + 6);
        const int h2 = wi * 7 + ky, w2 = wj * 7 + kx;
        const int rj = (h2 < 7 ? 0 : (h2 < 11 ? 1 : 2)) * 3 + (w2 < 7 ? 0 : (w2 < 11 ? 1 : 2));
        v = rel_bias[bidx * 16 + head] + ((ri != rj) ? -100.f : 0.f);
      }
      vv[r] = v;
    }
    ov.x = vv[0]; ov.y = vv[1]; ov.z = vv[2]; ov.w = vv[3];
    *(float4*)(BM + ((long)(hw * 16 + tile) << 8) + l * 4) = ov;
  }
}

// ---------- 4x4 byte transpose ----------
__device__ __forceinline__ void tr4(const uint32_t d[4], uint32_t o[4]) {
  #pragma unroll
  for (int c = 0; c < 4; ++c)
    o[c] = ((d[0] >> (8 * c)) & 0xffu) | (((d[1] >> (8 * c)) & 0xffu) << 8)
         | (((d[2] >> (8 * c)) & 0xffu) << 16) | (((d[3] >> (8 * c)) & 0xffu) << 24);
}

// ---------- MFMA windowed attention: one wave per (window, head); AT written frag-major ----------
__global__ __launch_bounds__(256)
void attn_mfma(const uint8_t* __restrict__ QKV, const float* __restrict__ BM,
               uint8_t* __restrict__ AT) {
  __shared__ uint8_t lds[4][9984];   // per-wave: Pb 64x72, Vt 32x72, Ot 64x48
  const int wave = threadIdx.x >> 6, lane = threadIdx.x & 63;
  const int n = lane & 15, g = lane >> 4;
  const int gw = blockIdx.x * 4 + wave;
  const int wd = gw >> 4, head = gw & 15;
  const int b = wd >> 2, wpos = wd & 3;
  const int wi = wpos >> 1, wj = wpos & 1;
  uint8_t* Pb = lds[wave];
  uint8_t* Vt = lds[wave] + 4608;
  uint8_t* Ot = lds[wave] + 6912;
  const long base = (long)b * 196 * 1536;
  auto tok = [&](int slot) -> int {
    const int ty = slot / 7, tx = slot - ty * 7;
    int h = wi * 7 + ty + 3; if (h >= 14) h -= 14;
    int w = wj * 7 + tx + 3; if (w >= 14) w -= 14;
    return h * 14 + w;
  };
  long Ak[4], Bq[4];
  #pragma unroll
  for (int t4 = 0; t4 < 4; ++t4) {
    int slot = t4 * 16 + n; if (slot > 48) slot = 48;
    const long tb = base + (long)tok(slot) * 1536 + head * 32 + g * 8;
    Bq[t4] = *(const long*)(QKV + tb);          // Q rows (B operand)
    Ak[t4] = *(const long*)(QKV + tb + 512);    // K rows (A operand)
  }
  #pragma unroll
  for (int bb2 = 0; bb2 < 2; ++bb2) {
    const int blk = lane + bb2 * 64;
    const int dq = blk >> 4, tq = blk & 15;
    uint32_t d4[4], o4[4];
    #pragma unroll
    for (int r = 0; r < 4; ++r) {
      int slot = tq * 4 + r; if (slot > 48) slot = 48;
      d4[r] = *(const uint32_t*)(QKV + base + (long)tok(slot) * 1536 + 1024 + head * 32 + dq * 4);
    }
    tr4(d4, o4);
    #pragma unroll
    for (int c = 0; c < 4; ++c)
      *(uint32_t*)(Vt + (dq * 4 + c) * 72 + tq * 4) = o4[c];
  }
  floatx4 acc[4][4];
  const float* bmw = BM + ((long)(head * 4 + wpos) << 12) + lane * 4;
  #pragma unroll
  for (int qi = 0; qi < 4; ++qi)
    #pragma unroll
    for (int ti = 0; ti < 4; ++ti) {
      const float4 bv = *(const float4*)(bmw + ((qi * 4 + ti) << 8));
      acc[qi][ti][0] = bv.x; acc[qi][ti][1] = bv.y;
      acc[qi][ti][2] = bv.z; acc[qi][ti][3] = bv.w;
    }
  #pragma unroll
  for (int qi = 0; qi < 4; ++qi)
    #pragma unroll
    for (int ti = 0; ti < 4; ++ti)
      acc[qi][ti] = __builtin_amdgcn_mfma_f32_16x16x32_fp8_fp8(Ak[ti], Bq[qi], acc[qi][ti], 0, 0, 0);
  #pragma unroll
  for (int qi = 0; qi < 4; ++qi) {
    float mx = -3.0e38f;
    #pragma unroll
    for (int ti = 0; ti < 4; ++ti)
      #pragma unroll
      for (int r = 0; r < 4; ++r) mx = fmaxf(mx, acc[qi][ti][r]);
    mx = fmaxf(mx, __shfl_xor(mx, 16));
    mx = fmaxf(mx, __shfl_xor(mx, 32));
    float sum = 0.f;
    #pragma unroll
    for (int ti = 0; ti < 4; ++ti)
      #pragma unroll
      for (int r = 0; r < 4; ++r) {
        const float e = __expf(acc[qi][ti][r] - mx);
        acc[qi][ti][r] = e; sum += e;
      }
    sum += __shfl_xor(sum, 16);
    sum += __shfl_xor(sum, 32);
    const float inv = 1.f / sum;
    #pragma unroll
    for (int ti = 0; ti < 4; ++ti) {
      const int pw = pk_fp8x4(acc[qi][ti][0] * inv, acc[qi][ti][1] * inv,
                              acc[qi][ti][2] * inv, acc[qi][ti][3] * inv);
      *(uint32_t*)(Pb + (qi * 16 + n) * 72 + ti * 16 + g * 4) = pw;
    }
  }
  asm volatile("s_waitcnt lgkmcnt(0)" ::: "memory");
  long Bv[2][2];
  #pragma unroll
  for (int ni = 0; ni < 2; ++ni)
    #pragma unroll
    for (int s = 0; s < 2; ++s)
      Bv[ni][s] = *(const long*)(Vt + (ni * 16 + n) * 72 + s * 32 + g * 8);
  floatx4 o[4][2] = {};
  #pragma unroll
  for (int qi = 0; qi < 4; ++qi)
    #pragma unroll
    for (int s = 0; s < 2; ++s) {
      const long Ap = *(const long*)(Pb + (qi * 16 + n) * 72 + s * 32 + g * 8);
      #pragma unroll
      for (int ni = 0; ni < 2; ++ni)
        o[qi][ni] = __builtin_amdgcn_mfma_f32_16x16x32_fp8_fp8(Ap, Bv[ni][s], o[qi][ni], 0, 0, 0);
    }
  #pragma unroll
  for (int qi = 0; qi < 4; ++qi)
    #pragma unroll
    for (int ni = 0; ni < 2; ++ni)
      #pragma unroll
      for (int r = 0; r < 4; ++r)
        Ot[(qi * 16 + g * 4 + r) * 48 + ni * 16 + n] =
            (uint8_t)(pk_fp8<false>(o[qi][ni][r], 0.f, 0) & 0xff);
  asm volatile("s_waitcnt lgkmcnt(0)" ::: "memory");
  if (lane < 49) {
    const int m = b * 196 + tok(lane);
    uint8_t* opb = AT + (long)(m & ~15) * 512 + ((m & 15) << 3);
    #pragma unroll
    for (int d8 = 0; d8 < 4; ++d8)
      *(long*)(opb + (head * 4 + d8) * 128) = *(const long*)(Ot + lane * 48 + d8 * 8);
  }
}

extern "C" void kernel_launch(void* const* d_in, const int* in_sizes, int n_in,
                              void* d_out, int out_size, void* d_ws, size_t ws_size,
                              hipStream_t stream) {
  const float* x      = (const float*)d_in[0];
  const float* ln1_w  = (const float*)d_in[1];
  const float* ln1_b  = (const float*)d_in[2];
  const float* qkv_w  = (const float*)d_in[3];
  const float* qkv_b  = (const float*)d_in[4];
  const float* relb   = (const float*)d_in[5];
  const float* proj_w = (const float*)d_in[6];
  const float* proj_b = (const float*)d_in[7];
  const float* gamma1 = (const float*)d_in[8];
  const float* ln2_w  = (const float*)d_in[9];
  const float* ln2_b  = (const float*)d_in[10];
  const float* fc1_w  = (const float*)d_in[11];
  const float* fc1_b  = (const float*)d_in[12];
  const float* fc2_w  = (const float*)d_in[13];
  const float* fc2_b  = (const float*)d_in[14];
  const float* gamma2 = (const float*)d_in[15];
  float* out = (float*)d_out;
  char* ws = (char*)d_ws;

  float*    mu1 = (float*)(ws + 0);
  float*    rs1 = (float*)(ws + 100352);
  float*    S1  = (float*)(ws + 200704);      // LN2 raw sum
  float*    S2  = (float*)(ws + 301056);      // LN2 raw sumsq
  uint8_t*  Wq  = (uint8_t*)(ws + 401408);    //   786,432 B (MX-B layout)
  uint8_t*  Wp  = (uint8_t*)(ws + 1187840);   //   262,144 B frag-major
  uint8_t*  W1  = (uint8_t*)(ws + 1449984);   // 1,048,576 B (MX-B layout)
  uint8_t*  W2  = (uint8_t*)(ws + 2498560);   // 1,048,576 B frag-major
  float*    BMt = (float*)  (ws + 3547136);   // 1,048,576 B bias+mask table
  uint8_t*  Afp = (uint8_t*)(ws + 4595712);   // 12,845,056 B tokens (MX-A: LN1, later LN2)
  float*    Xt  = (float*)  (ws + 17440768);  // 51,380,224 B token-major f32 x copy (R13)
  uint16_t* X1b = (uint16_t*)(ws + 68820992); // 25,690,112 B token-major bf16
  uint8_t*  QKV = (uint8_t*)(ws + 120201216); // 38,535,168 B token-major fp8
  uint8_t*  AT  = (uint8_t*)(ws + 158736384); // 12,845,056 B frag-major fp8
  uint8_t*  Hb  = (uint8_t*)(ws + 120201216); // 51,380,224 B 16x16 frag-major, overlaps dead QKV+AT

  // zero LN2 sum buffers (atomics accumulate during proj epilogue)
  hipMemsetAsync(ws + 200704, 0, 200704, stream);

  // weights -> fp8 (MX-B for qkv/fc1; 16x16 frag for proj/fc2), BM table
  cvt_frag_mx512<<<768,  256, 0, stream>>>(qkv_w, Wq, 196608);
  cvt_frag<512> <<<256,  256, 0, stream>>>(proj_w, Wp, 65536);
  cvt_frag_mx512<<<1024, 256, 0, stream>>>(fc1_w, W1, 262144);
  cvt_frag<2048><<<1024, 256, 0, stream>>>(fc2_w, W2, 262144);
  bm_build<<<64, 256, 0, stream>>>(relb, BMt);

  // LN1 -> MX-A fp8 tokens + token-major f32 x copy
  ln_stats_nchw<<<392, 256, 0, stream>>>(x, mu1, rs1);
  ln1_apply<<<4096, 256, 0, stream>>>(x, mu1, rs1, ln1_w, ln1_b, Afp, Xt);

  // qkv: MX 32x32x64 GEMM (q pre-scaled) -> token-major QKV: grid 8*13*24 = 2496
  gemm_mx_qkv<<<2496, 256, 0, stream>>>(Afp, Wq, qkv_b, QKV);

  // shifted-window attention (MFMA), frag-major AT out
  attn_mfma<<<2048, 256, 0, stream>>>(QKV, BMt, AT);

  // proj GEMM: X1b(bf16) = Xt + g1*(out+b); fused LN2 stats: T=98, NG=8 -> 832
  gemm_bl<4, 512, 1, 8, 98><<<832, 256, 0, stream>>>(AT, Wp, proj_b, Xt, nullptr, gamma1, nullptr, nullptr, X1b, S1, S2, 512);

  // LN2 apply -> MX-A fp8 tokens
  ln2_panel<<<1568, 256, 0, stream>>>(X1b, S1, S2, ln2_w, ln2_b, Afp);

  // fc1: MX-scaled 32x32x64 GEMM + GELU -> Hb (16x16 frag): grid 8*13*32 = 3328
  gemm_mx_fc1<<<3328, 256, 0, stream>>>(Afp, W1, fc1_b, Hb);

  // fc2 (T=196, NG=8 -> 1600) -> NCHW out via LDS exchange
  gemm_bl<2, 2048, 3, 8, 196><<<1600, 256, 0, stream>>>(Hb, W2, fc2_b, nullptr, X1b, gamma2, nullptr, out, nullptr, nullptr, nullptr, 512);
}